// Round 1
// baseline (990.769 us; speedup 1.0000x reference)
//
#include <hip/hip_runtime.h>
#include <cstdint>
#include <cstddef>

// ---------------------------------------------------------------------------
// Faster-RCNN forward, MI355X (gfx950).
// fp32 everywhere except: feat(NHWC) / roi-features(A) / fc1_w / fc2_w / h1
// which are bf16 for the MFMA GEMMs. RPN->topk path is pure fp32 so the
// top-1000 ordering matches the numpy reference.
// ---------------------------------------------------------------------------

typedef float  f4  __attribute__((ext_vector_type(4)));
typedef short  s8v __attribute__((ext_vector_type(8)));

__device__ __forceinline__ unsigned short f2bf(float f) {
  unsigned int u = __builtin_bit_cast(unsigned int, f);
  u += 0x7FFFu + ((u >> 16) & 1u);           // RNE
  return (unsigned short)(u >> 16);
}
__device__ __forceinline__ float bf2f(unsigned short h) {
  unsigned int u = ((unsigned int)h) << 16;
  return __builtin_bit_cast(float, u);
}

#define BBOX_CLAMP_F 4.135166556742356f

// ------------------------------ conv0: 3->64, 7x7, s2, p3, fused norm+ReLU --
__global__ __launch_bounds__(256, 2) void conv0_kernel(
    const float* __restrict__ img, const float* __restrict__ w,
    const float* __restrict__ bias, float* __restrict__ out) {
  __shared__ float patch[3][37][40];
  __shared__ float wlds[64][3][7][8];
  const int tid = threadIdx.x;
  const int tx0 = blockIdx.x * 16, ty0 = blockIdx.y * 16;
  for (int idx = tid; idx < 3 * 37 * 40; idx += 256) {
    int c = idx / 1480; int rem = idx - c * 1480; int r = rem / 40; int col = rem - r * 40;
    float v = 0.f;
    int iy = ty0 * 2 - 3 + r, ix = tx0 * 2 - 3 + col;
    if (col < 37 && iy >= 0 && iy < 512 && ix >= 0 && ix < 512) {
      float mval = (c == 0) ? 0.485f : (c == 1) ? 0.456f : 0.406f;
      float sval = (c == 0) ? 0.229f : (c == 1) ? 0.224f : 0.225f;
      v = (img[c * 262144 + iy * 512 + ix] - mval) / sval;
    }
    (&patch[0][0][0])[idx] = v;
  }
  for (int idx = tid; idx < 64 * 3 * 7 * 8; idx += 256) {
    int oc = idx / 168; int rem = idx - oc * 168; int c = rem / 56;
    int rem2 = rem - c * 56; int ky = rem2 >> 3; int kx = rem2 & 7;
    (&wlds[0][0][0][0])[idx] = (kx < 7) ? w[oc * 147 + c * 49 + ky * 7 + kx] : 0.f;
  }
  __syncthreads();
  const int ocg = tid >> 5, cell = tid & 31;
  const int cx = cell & 3, cy = cell >> 2;
  float acc[8][2][4] = {};
  for (int c = 0; c < 3; ++c) {
    for (int ky = 0; ky < 7; ++ky) {
      const float* p0 = &patch[c][cy * 4 + ky][cx * 8];
      const float* p1 = &patch[c][cy * 4 + ky + 2][cx * 8];
      f4 a0[4], a1[4];
      #pragma unroll
      for (int q = 0; q < 4; ++q) { a0[q] = *(const f4*)(p0 + q * 4); a1[q] = *(const f4*)(p1 + q * 4); }
      #pragma unroll
      for (int oc = 0; oc < 8; ++oc) {
        const float* wp = &wlds[ocg * 8 + oc][c][ky][0];
        f4 w0 = *(const f4*)wp, w1 = *(const f4*)(wp + 4);
        #pragma unroll
        for (int kx = 0; kx < 7; ++kx) {
          float wv = (kx < 4) ? w0[kx] : w1[kx - 4];
          #pragma unroll
          for (int x = 0; x < 4; ++x) {
            int e = x * 2 + kx;
            acc[oc][0][x] += a0[e >> 2][e & 3] * wv;
            acc[oc][1][x] += a1[e >> 2][e & 3] * wv;
          }
        }
      }
    }
  }
  #pragma unroll
  for (int oc = 0; oc < 8; ++oc) {
    float b = bias[ocg * 8 + oc];
    #pragma unroll
    for (int r = 0; r < 2; ++r) {
      f4 v;
      #pragma unroll
      for (int x = 0; x < 4; ++x) v[x] = fmaxf(acc[oc][r][x] + b, 0.f);
      *(f4*)&out[(size_t)(ocg * 8 + oc) * 65536 + (size_t)(ty0 + cy * 2 + r) * 256 + tx0 + cx * 4] = v;
    }
  }
}

// ------------------------------ maxpool 3x3 s2 p1: 64x256x256 -> 64x128x128 -
__global__ __launch_bounds__(256) void maxpool_kernel(
    const float* __restrict__ in, float* __restrict__ out) {
  int i = blockIdx.x * 256 + threadIdx.x;           // 64*128*128
  int c = i >> 14; int y = (i >> 7) & 127; int x = i & 127;
  float m = -INFINITY;
  #pragma unroll
  for (int dy = 0; dy < 3; ++dy) {
    int yy = 2 * y - 1 + dy;
    if (yy < 0 || yy >= 256) continue;
    #pragma unroll
    for (int dx = 0; dx < 3; ++dx) {
      int xx = 2 * x - 1 + dx;
      if (xx < 0 || xx >= 256) continue;
      m = fmaxf(m, in[c * 65536 + yy * 256 + xx]);
    }
  }
  out[i] = m;
}

// ------------------------------ generic 3x3 conv (partials over c-split) ----
template<int CIN, int COUT, int HIN, int HOUT, int STR, int TILES_X>
__global__ __launch_bounds__(256, 2) void conv3x3_kernel(
    const float* __restrict__ in, const float* __restrict__ w,
    float* __restrict__ parts) {
  constexpr int TW = 16, TH = 16;
  constexpr int SPAN  = (TH - 1) * STR + 3;
  constexpr int SPANW = (TW - 1) * STR + 3;
  constexpr int PADW  = (SPANW + 3) & ~3;
  constexpr int CSPL  = 32;
  __shared__ float patch[8][SPAN][PADW];
  __shared__ float wlds[32][8][3][4];
  const int tid = threadIdx.x;
  const int tile = blockIdx.x;
  const int tx0 = (tile % TILES_X) * TW, ty0 = (tile / TILES_X) * TH;
  const int ocb = blockIdx.y * 32;
  const int cb0 = blockIdx.z * CSPL;
  const int ocg = tid >> 5, cell = tid & 31;
  const int cx = cell & 3, cy = cell >> 2;
  float acc[4][2][4] = {};
  for (int cc = 0; cc < CSPL / 8; ++cc) {
    int cbase = cb0 + cc * 8;
    __syncthreads();
    for (int idx = tid; idx < 8 * SPAN * PADW; idx += 256) {
      int ch = idx / (SPAN * PADW);
      int rem = idx - ch * (SPAN * PADW);
      int r = rem / PADW;
      int col = rem - r * PADW;
      float v = 0.f;
      int iy = ty0 * STR - 1 + r, ix = tx0 * STR - 1 + col;
      if (col < SPANW && iy >= 0 && iy < HIN && ix >= 0 && ix < HIN)
        v = in[(size_t)(cbase + ch) * (HIN * HIN) + iy * HIN + ix];
      (&patch[0][0][0])[idx] = v;
    }
    for (int idx = tid; idx < 32 * 8 * 3 * 4; idx += 256) {
      int oc = idx / 96;
      int rem = idx - oc * 96;
      int ch = rem / 12;
      int rem2 = rem - ch * 12;
      int ky = rem2 >> 2, kx = rem2 & 3;
      (&wlds[0][0][0][0])[idx] = (kx < 3)
        ? w[((size_t)(ocb + oc) * CIN + cbase + ch) * 9 + ky * 3 + kx] : 0.f;
    }
    __syncthreads();
    #pragma unroll 1
    for (int ch = 0; ch < 8; ++ch) {
      #pragma unroll
      for (int ky = 0; ky < 3; ++ky) {
        constexpr int NF = (STR == 2) ? 3 : 2;
        const float* p0 = &patch[ch][(cy * 2 + 0) * STR + ky][cx * 4 * STR];
        const float* p1 = &patch[ch][(cy * 2 + 1) * STR + ky][cx * 4 * STR];
        f4 a0[NF], a1[NF];
        #pragma unroll
        for (int q = 0; q < NF; ++q) { a0[q] = *(const f4*)(p0 + q * 4); a1[q] = *(const f4*)(p1 + q * 4); }
        #pragma unroll
        for (int oc = 0; oc < 4; ++oc) {
          f4 wv = *(const f4*)&wlds[ocg * 4 + oc][ch][ky][0];
          #pragma unroll
          for (int kx = 0; kx < 3; ++kx) {
            #pragma unroll
            for (int x = 0; x < 4; ++x) {
              int e = x * STR + kx;
              acc[oc][0][x] += a0[e >> 2][e & 3] * wv[kx];
              acc[oc][1][x] += a1[e >> 2][e & 3] * wv[kx];
            }
          }
        }
      }
    }
  }
  size_t zb = (size_t)blockIdx.z * COUT * HOUT * HOUT;
  #pragma unroll
  for (int oc = 0; oc < 4; ++oc) {
    #pragma unroll
    for (int r = 0; r < 2; ++r) {
      f4 v;
      #pragma unroll
      for (int x = 0; x < 4; ++x) v[x] = acc[oc][r][x];
      *(f4*)&parts[zb + (size_t)(ocb + ocg * 4 + oc) * (HOUT * HOUT)
                   + (size_t)(ty0 + cy * 2 + r) * HOUT + tx0 + cx * 4] = v;
    }
  }
}

// ------------------------------ partial-sum + bias + relu (+ optional NHWC bf16)
template<int NS>
__global__ __launch_bounds__(256) void reduce_conv_kernel(
    const float* __restrict__ parts, const float* __restrict__ bias,
    float* __restrict__ out, int total, int hwshift,
    unsigned short* __restrict__ nhwc, int C) {
  int i = blockIdx.x * 256 + threadIdx.x;
  if (i >= total) return;
  float s = 0.f;
  #pragma unroll
  for (int k = 0; k < NS; ++k) s += parts[(size_t)k * total + i];
  int c = i >> hwshift;
  s += bias[c];
  s = fmaxf(s, 0.f);
  out[i] = s;
  if (nhwc) {
    int hw = 1 << hwshift;
    int px = i & (hw - 1);
    nhwc[(size_t)px * C + c] = f2bf(s);
  }
}

// ------------------------------ RPN 1x1 heads ------------------------------
__global__ __launch_bounds__(64) void rpn_head_kernel(
    const float* __restrict__ t, const float* __restrict__ wc,
    const float* __restrict__ bc, const float* __restrict__ wb,
    const float* __restrict__ bb, float* __restrict__ objf,
    float* __restrict__ bdf) {
  int px = blockIdx.x, lane = threadIdx.x;
  float acc[45] = {};
  for (int j = 0; j < 8; ++j) {
    int c = j * 64 + lane;
    float tv = t[c * 256 + px];
    #pragma unroll
    for (int a = 0; a < 9; ++a) acc[a] += tv * wc[a * 512 + c];
    #pragma unroll
    for (int o = 0; o < 36; ++o) acc[9 + o] += tv * wb[o * 512 + c];
  }
  #pragma unroll
  for (int o = 0; o < 45; ++o) {
    #pragma unroll
    for (int m = 32; m; m >>= 1) acc[o] += __shfl_xor(acc[o], m);
  }
  if (lane == 0) {
    #pragma unroll
    for (int a = 0; a < 9; ++a) objf[px * 9 + a] = acc[a] + bc[a];
    #pragma unroll
    for (int a = 0; a < 9; ++a)
      #pragma unroll
      for (int q = 0; q < 4; ++q)
        bdf[(px * 9 + a) * 4 + q] = acc[9 + a * 4 + q] + bb[a * 4 + q];
  }
}

// ------------------------------ anchor decode -> props (pre-clipped) -------
__device__ const float g_W2[9] = {91.f, 181.f, 362.f, 64.f, 128.f, 256.f, 45.f, 91.f, 181.f};
__device__ const float g_H2[9] = {45.f, 91.f, 181.f, 64.f, 128.f, 256.f, 91.f, 181.f, 362.f};

__global__ __launch_bounds__(256) void props_kernel(
    const float* __restrict__ bdf, float* __restrict__ props) {
  int i = blockIdx.x * 256 + threadIdx.x;
  if (i >= 2304) return;
  int pix = i / 9; int a = i - pix * 9;
  int y = pix >> 4, x = pix & 15;
  float wid = 2.f * g_W2[a], hei = 2.f * g_H2[a];
  float cx = (float)(x * 32), cy = (float)(y * 32);
  float dx = bdf[i * 4 + 0], dy = bdf[i * 4 + 1];
  float dw = fminf(bdf[i * 4 + 2], BBOX_CLAMP_F);
  float dh = fminf(bdf[i * 4 + 3], BBOX_CLAMP_F);
  float pcx = dx * wid + cx, pcy = dy * hei + cy;
  float pw = expf(dw) * wid, ph = expf(dh) * hei;
  props[i * 4 + 0] = fminf(fmaxf(pcx - 0.5f * pw, 0.f), 512.f);
  props[i * 4 + 1] = fminf(fmaxf(pcy - 0.5f * ph, 0.f), 512.f);
  props[i * 4 + 2] = fminf(fmaxf(pcx + 0.5f * pw, 0.f), 512.f);
  props[i * 4 + 3] = fminf(fmaxf(pcy + 0.5f * ph, 0.f), 512.f);
}

// ------------------------------ exact stable top-1000 by rank --------------
__global__ __launch_bounds__(256) void topk_kernel(
    const float* __restrict__ objf, const float* __restrict__ props,
    float* __restrict__ rois) {
  __shared__ float v[2304];
  int tid = threadIdx.x;
  for (int idx = tid; idx < 2304; idx += 256) v[idx] = objf[idx];
  __syncthreads();
  int i = blockIdx.x * 256 + tid;
  float vi = v[i];
  int rank = 0;
  for (int j = 0; j < 2304; ++j) {
    float vj = v[j];
    rank += (vj > vi) || (vj == vi && j < i);
  }
  if (rank < 1000) {
    f4 p = *(const f4*)(props + i * 4);
    *(f4*)(rois + rank * 4) = p;
  }
}

// ------------------------------ ROI-align -> A (bf16, k = c*49 + p) --------
__global__ __launch_bounds__(512) void roi_align_kernel(
    const float* __restrict__ rois, const unsigned short* __restrict__ featn,
    unsigned short* __restrict__ A) {
  __shared__ int   pidx[49][16];
  __shared__ float pwg[49][16];
  int m = blockIdx.x, tid = threadIdx.x;
  if (tid < 49) {
    int qy = tid / 7, qx = tid - qy * 7;
    float x1 = rois[m * 4 + 0] * 0.03125f;
    float y1 = rois[m * 4 + 1] * 0.03125f;
    float x2 = rois[m * 4 + 2] * 0.03125f;
    float y2 = rois[m * 4 + 3] * 0.03125f;
    float rw = fmaxf(x2 - x1, 1.f), rh = fmaxf(y2 - y1, 1.f);
    float wsx[2][2]; int xsx[2][2];
    float wsy[2][2]; int ysy[2][2];
    #pragma unroll
    for (int s = 0; s < 2; ++s) {
      float gx = ((float)(2 * qx + s) + 0.5f) / 14.f;
      float px = fminf(fmaxf(x1 + gx * rw, 0.f), 15.f);
      int x0 = (int)floorf(px);
      int x1i = min(x0 + 1, 15);
      float lx = px - (float)x0;
      xsx[s][0] = x0; xsx[s][1] = x1i; wsx[s][0] = 1.f - lx; wsx[s][1] = lx;
      float gy = ((float)(2 * qy + s) + 0.5f) / 14.f;
      float py = fminf(fmaxf(y1 + gy * rh, 0.f), 15.f);
      int y0 = (int)floorf(py);
      int y1i = min(y0 + 1, 15);
      float ly = py - (float)y0;
      ysy[s][0] = y0; ysy[s][1] = y1i; wsy[s][0] = 1.f - ly; wsy[s][1] = ly;
    }
    int e = 0;
    #pragma unroll
    for (int sy = 0; sy < 2; ++sy)
      #pragma unroll
      for (int cyi = 0; cyi < 2; ++cyi)
        #pragma unroll
        for (int sx = 0; sx < 2; ++sx)
          #pragma unroll
          for (int cxi = 0; cxi < 2; ++cxi) {
            pwg[tid][e] = 0.25f * wsy[sy][cyi] * wsx[sx][cxi];
            pidx[tid][e] = (ysy[sy][cyi] * 16 + xsx[sx][cxi]) * 512;
            ++e;
          }
  }
  __syncthreads();
  int c = tid;
  const unsigned short* F = featn + c;
  unsigned short* outp = A + (size_t)m * 25088 + (size_t)c * 49;
  for (int p = 0; p < 49; ++p) {
    float a = 0.f;
    #pragma unroll
    for (int e = 0; e < 16; ++e)
      a += pwg[p][e] * bf2f(F[pidx[p][e]]);
    outp[p] = f2bf(a);
  }
}

// ------------------------------ fp32 (K,N) -> bf16 (N,K) transpose ---------
__global__ __launch_bounds__(256) void transpose_bf16_kernel(
    const float* __restrict__ src, unsigned short* __restrict__ dst,
    int K, int N) {
  __shared__ float tile[64][65];
  int k0 = blockIdx.x * 64, n0 = blockIdx.y * 64;
  int tid = threadIdx.x;
  int rr = tid >> 4, c4 = tid & 15;
  #pragma unroll
  for (int j = 0; j < 4; ++j) {
    int r = rr + j * 16;
    f4 v = *(const f4*)(src + (size_t)(k0 + r) * N + n0 + c4 * 4);
    tile[r][c4 * 4 + 0] = v[0]; tile[r][c4 * 4 + 1] = v[1];
    tile[r][c4 * 4 + 2] = v[2]; tile[r][c4 * 4 + 3] = v[3];
  }
  __syncthreads();
  int nl = tid >> 2;
  int kc = (tid & 3) * 16;
  unsigned int u[8];
  #pragma unroll
  for (int i = 0; i < 8; ++i) {
    unsigned int lo = f2bf(tile[kc + 2 * i][nl]);
    unsigned int hi = f2bf(tile[kc + 2 * i + 1][nl]);
    u[i] = lo | (hi << 16);
  }
  uint4* dp = (uint4*)(dst + (size_t)(n0 + nl) * K + k0 + kc);
  dp[0] = make_uint4(u[0], u[1], u[2], u[3]);
  dp[1] = make_uint4(u[4], u[5], u[6], u[7]);
}

// ------------------------------ bf16 GEMM  C = A(MxK) * B^T(NxK), split-K --
__global__ __launch_bounds__(256, 2) void gemm_bt_kernel(
    const unsigned short* __restrict__ A, const unsigned short* __restrict__ B,
    float* __restrict__ parts, int K, int nsteps) {
  __shared__ unsigned short As[128 * 32];
  __shared__ unsigned short Bs[128 * 32];
  const int tid = threadIdx.x;
  const int lane = tid & 63, wave = tid >> 6;
  const int n0 = blockIdx.x * 128, m0 = blockIdx.y * 128, ks = blockIdx.z;
  const int kbase = ks * nsteps * 32;
  f4 acc[4][4] = {};
  const int wr = wave >> 1, wc = wave & 1;
  const int rsel = lane & 15, ksel = (lane >> 4) * 8;
  for (int s = 0; s < nsteps; ++s) {
    int kk = kbase + s * 32;
    #pragma unroll
    for (int j = 0; j < 2; ++j) {
      int c_ = j * 256 + tid;
      int row = c_ >> 2;
      int k8 = (c_ & 3) << 3;
      __builtin_amdgcn_global_load_lds(
          (const __attribute__((address_space(1))) void*)(A + (size_t)(m0 + row) * K + kk + k8),
          (__attribute__((address_space(3))) void*)(As + c_ * 8), 16, 0, 0);
      __builtin_amdgcn_global_load_lds(
          (const __attribute__((address_space(1))) void*)(B + (size_t)(n0 + row) * K + kk + k8),
          (__attribute__((address_space(3))) void*)(Bs + c_ * 8), 16, 0, 0);
    }
    __syncthreads();
    s8v af[4], bfr[4];
    #pragma unroll
    for (int m = 0; m < 4; ++m)
      af[m] = *(const s8v*)(As + (wr * 64 + m * 16 + rsel) * 32 + ksel);
    #pragma unroll
    for (int n = 0; n < 4; ++n)
      bfr[n] = *(const s8v*)(Bs + (wc * 64 + n * 16 + rsel) * 32 + ksel);
    #pragma unroll
    for (int m = 0; m < 4; ++m)
      #pragma unroll
      for (int n = 0; n < 4; ++n)
        acc[m][n] = __builtin_amdgcn_mfma_f32_16x16x32_bf16(af[m], bfr[n], acc[m][n], 0, 0, 0);
    __syncthreads();
  }
  float* outp = parts + (size_t)ks * 1048576;
  int rb = m0 + wr * 64 + ((lane >> 4) << 2);
  int cb = n0 + wc * 64 + (lane & 15);
  #pragma unroll
  for (int m = 0; m < 4; ++m)
    #pragma unroll
    for (int n = 0; n < 4; ++n)
      #pragma unroll
      for (int i = 0; i < 4; ++i)
        outp[(size_t)(rb + m * 16 + i) * 1024 + cb + n * 16] = acc[m][n][i];
}

// ------------------------------ GEMM reductions ----------------------------
__global__ __launch_bounds__(256) void reduce_fc1_kernel(
    const float* __restrict__ parts, const float* __restrict__ bias,
    unsigned short* __restrict__ h1b) {
  int i4 = blockIdx.x * 256 + threadIdx.x;        // 1024*1024/4
  const f4* p4 = (const f4*)parts;
  f4 s = {0.f, 0.f, 0.f, 0.f};
  #pragma unroll
  for (int k = 0; k < 8; ++k) s += p4[(size_t)k * 262144 + i4];
  f4 b = ((const f4*)bias)[i4 & 255];
  s += b;
  unsigned int lo = (unsigned int)f2bf(fmaxf(s[0], 0.f)) | ((unsigned int)f2bf(fmaxf(s[1], 0.f)) << 16);
  unsigned int hi = (unsigned int)f2bf(fmaxf(s[2], 0.f)) | ((unsigned int)f2bf(fmaxf(s[3], 0.f)) << 16);
  ((uint2*)h1b)[i4] = make_uint2(lo, hi);
}

__global__ __launch_bounds__(256) void reduce_fc2_kernel(
    const float* __restrict__ parts, const float* __restrict__ bias,
    float* __restrict__ h2) {
  int i4 = blockIdx.x * 256 + threadIdx.x;
  const f4* p4 = (const f4*)parts;
  f4 s = p4[i4] + p4[262144 + i4];
  f4 b = ((const f4*)bias)[i4 & 255];
  s += b;
  #pragma unroll
  for (int j = 0; j < 4; ++j) s[j] = fmaxf(s[j], 0.f);
  ((f4*)h2)[i4] = s;
}

// ------------------------------ final heads + softmax + decode -------------
__global__ __launch_bounds__(64) void heads_kernel(
    const float* __restrict__ h2, const float* __restrict__ cw,
    const float* __restrict__ cb, const float* __restrict__ bw,
    const float* __restrict__ bb, const float* __restrict__ rois,
    float* __restrict__ outp) {
  int m = blockIdx.x, lane = threadIdx.x;
  __shared__ float vals[32];
  if (lane < 30) {
    bool is_cls = lane < 6;
    int o = is_cls ? lane : lane - 6;
    const float* wp = is_cls ? cw : bw;
    int st = is_cls ? 6 : 24;
    const float* hrow = h2 + (size_t)m * 1024;
    float a0 = 0.f, a1 = 0.f, a2 = 0.f, a3 = 0.f;
    for (int k = 0; k < 1024; k += 4) {
      a0 += hrow[k + 0] * wp[(k + 0) * st + o];
      a1 += hrow[k + 1] * wp[(k + 1) * st + o];
      a2 += hrow[k + 2] * wp[(k + 2) * st + o];
      a3 += hrow[k + 3] * wp[(k + 3) * st + o];
    }
    vals[lane] = a0 + a1 + a2 + a3 + (is_cls ? cb[o] : bb[o]);
  }
  __syncthreads();
  if (lane < 5) {
    int cls = lane + 1;
    float mx = vals[0];
    #pragma unroll
    for (int o = 1; o < 6; ++o) mx = fmaxf(mx, vals[o]);
    float den = 0.f;
    #pragma unroll
    for (int o = 0; o < 6; ++o) den += expf(vals[o] - mx);
    float score = expf(vals[cls] - mx) / den;
    float x1 = rois[m * 4 + 0], y1 = rois[m * 4 + 1];
    float x2 = rois[m * 4 + 2], y2 = rois[m * 4 + 3];
    float w_ = x2 - x1, h_ = y2 - y1;
    float cxx = x1 + 0.5f * w_, cyy = y1 + 0.5f * h_;
    float dx = vals[6 + cls * 4 + 0] / 10.f;
    float dy = vals[6 + cls * 4 + 1] / 10.f;
    float dw = fminf(vals[6 + cls * 4 + 2] / 5.f, BBOX_CLAMP_F);
    float dh = fminf(vals[6 + cls * 4 + 3] / 5.f, BBOX_CLAMP_F);
    float pcx = dx * w_ + cxx, pcy = dy * h_ + cyy;
    float pw = expf(dw) * w_, ph = expf(dh) * h_;
    float* op = outp + m * 25 + lane * 5;
    op[0] = fminf(fmaxf(pcx - 0.5f * pw, 0.f), 512.f);
    op[1] = fminf(fmaxf(pcy - 0.5f * ph, 0.f), 512.f);
    op[2] = fminf(fmaxf(pcx + 0.5f * pw, 0.f), 512.f);
    op[3] = fminf(fmaxf(pcy + 0.5f * ph, 0.f), 512.f);
    op[4] = score;
  }
}

// ---------------------------------------------------------------------------
// workspace layout (bytes). Total ~140 MB with heavy overlap:
//   [0, 52MB)  : A (1024x25088 bf16) -- earlier reused for conv chain+partials
//   [52, 54MB) : feat / feat_nhwc / t / objf / bdf / props / rois
//   [54,106MB) : Bt1 (bf16) -- later reused for h1b / Bt2 / parts2 / h2
//   [106,140MB): parts1 (8 x 4MB fp32)
// ---------------------------------------------------------------------------
static constexpr size_t MB_ = 1024ull * 1024ull;
static constexpr size_t A_OFF      = 0;
static constexpr size_t CONV0_OFF  = 0;
static constexpr size_t POOL_OFF   = 17 * MB_;
static constexpr size_t C1_OFF     = 22 * MB_;
static constexpr size_t C2_OFF     = 25 * MB_;
static constexpr size_t CPARTS_OFF = 27 * MB_;
static constexpr size_t FEAT_OFF   = 52 * MB_;
static constexpr size_t FEATN_OFF  = FEAT_OFF + 524288;
static constexpr size_t T_OFF      = FEATN_OFF + 262144;
static constexpr size_t OBJF_OFF   = T_OFF + 524288;
static constexpr size_t BDF_OFF    = OBJF_OFF + 16384;
static constexpr size_t PROPS_OFF  = BDF_OFF + 40960;
static constexpr size_t ROIS_OFF   = PROPS_OFF + 40960;
static constexpr size_t BT1_OFF    = 54 * MB_;
static constexpr size_t H1B_OFF    = BT1_OFF;              // after GEMM1
static constexpr size_t BT2_OFF    = BT1_OFF + 2 * MB_;
static constexpr size_t PARTS2_OFF = BT1_OFF + 4 * MB_;
static constexpr size_t H2_OFF     = BT1_OFF + 13 * MB_;
static constexpr size_t PARTS1_OFF = 106 * MB_;

extern "C" void kernel_launch(void* const* d_in, const int* in_sizes, int n_in,
                              void* d_out, int out_size, void* d_ws, size_t ws_size,
                              hipStream_t stream) {
  (void)in_sizes; (void)n_in; (void)out_size; (void)ws_size;
  const float* images     = (const float*)d_in[0];
  const float* c0_w       = (const float*)d_in[1];
  const float* c0_b       = (const float*)d_in[2];
  const float* c1_w       = (const float*)d_in[3];
  const float* c1_b       = (const float*)d_in[4];
  const float* c2_w       = (const float*)d_in[5];
  const float* c2_b       = (const float*)d_in[6];
  const float* c3_w       = (const float*)d_in[7];
  const float* c3_b       = (const float*)d_in[8];
  const float* rpn_conv_w = (const float*)d_in[9];
  const float* rpn_conv_b = (const float*)d_in[10];
  const float* rpn_cls_w  = (const float*)d_in[11];
  const float* rpn_cls_b  = (const float*)d_in[12];
  const float* rpn_bbox_w = (const float*)d_in[13];
  const float* rpn_bbox_b = (const float*)d_in[14];
  const float* fc1_w      = (const float*)d_in[15];
  const float* fc1_b      = (const float*)d_in[16];
  const float* fc2_w      = (const float*)d_in[17];
  const float* fc2_b      = (const float*)d_in[18];
  const float* cls_w      = (const float*)d_in[19];
  const float* cls_b      = (const float*)d_in[20];
  const float* bbox_w     = (const float*)d_in[21];
  const float* bbox_b     = (const float*)d_in[22];

  char* ws = (char*)d_ws;
  float* conv0  = (float*)(ws + CONV0_OFF);
  float* pool   = (float*)(ws + POOL_OFF);
  float* c1o    = (float*)(ws + C1_OFF);
  float* c2o    = (float*)(ws + C2_OFF);
  float* cparts = (float*)(ws + CPARTS_OFF);
  float* feat   = (float*)(ws + FEAT_OFF);
  unsigned short* featn = (unsigned short*)(ws + FEATN_OFF);
  float* tbuf   = (float*)(ws + T_OFF);
  float* objf   = (float*)(ws + OBJF_OFF);
  float* bdf    = (float*)(ws + BDF_OFF);
  float* props  = (float*)(ws + PROPS_OFF);
  float* rois   = (float*)(ws + ROIS_OFF);
  unsigned short* Abuf = (unsigned short*)(ws + A_OFF);
  unsigned short* Bt1  = (unsigned short*)(ws + BT1_OFF);
  unsigned short* h1b  = (unsigned short*)(ws + H1B_OFF);
  unsigned short* Bt2  = (unsigned short*)(ws + BT2_OFF);
  float* parts1 = (float*)(ws + PARTS1_OFF);
  float* parts2 = (float*)(ws + PARTS2_OFF);
  float* h2     = (float*)(ws + H2_OFF);
  float* outp   = (float*)d_out;

  // backbone
  conv0_kernel<<<dim3(16, 16), 256, 0, stream>>>(images, c0_w, c0_b, conv0);
  maxpool_kernel<<<4096, 256, 0, stream>>>(conv0, pool);
  conv3x3_kernel<64, 128, 128, 64, 2, 4><<<dim3(16, 4, 2), 256, 0, stream>>>(pool, c1_w, cparts);
  reduce_conv_kernel<2><<<2048, 256, 0, stream>>>(cparts, c1_b, c1o, 524288, 12, nullptr, 0);
  conv3x3_kernel<128, 256, 64, 32, 2, 2><<<dim3(4, 8, 4), 256, 0, stream>>>(c1o, c2_w, cparts);
  reduce_conv_kernel<4><<<1024, 256, 0, stream>>>(cparts, c2_b, c2o, 262144, 10, nullptr, 0);
  conv3x3_kernel<256, 512, 32, 16, 2, 1><<<dim3(1, 16, 8), 256, 0, stream>>>(c2o, c3_w, cparts);
  reduce_conv_kernel<8><<<512, 256, 0, stream>>>(cparts, c3_b, feat, 131072, 8, featn, 512);

  // RPN
  conv3x3_kernel<512, 512, 16, 16, 1, 1><<<dim3(1, 16, 16), 256, 0, stream>>>(feat, rpn_conv_w, cparts);
  reduce_conv_kernel<16><<<512, 256, 0, stream>>>(cparts, rpn_conv_b, tbuf, 131072, 8, nullptr, 0);
  rpn_head_kernel<<<256, 64, 0, stream>>>(tbuf, rpn_cls_w, rpn_cls_b, rpn_bbox_w, rpn_bbox_b, objf, bdf);
  props_kernel<<<9, 256, 0, stream>>>(bdf, props);
  topk_kernel<<<9, 256, 0, stream>>>(objf, props, rois);

  // ROI features (A), pad rows 1000..1023 to zero
  hipMemsetAsync(ws + A_OFF + (size_t)1000 * 25088 * 2, 0, (size_t)24 * 25088 * 2, stream);
  roi_align_kernel<<<1000, 512, 0, stream>>>(rois, featn, Abuf);

  // fc1: (1024x25088) x (25088x1024)
  transpose_bf16_kernel<<<dim3(392, 16), 256, 0, stream>>>(fc1_w, Bt1, 25088, 1024);
  gemm_bt_kernel<<<dim3(8, 8, 8), 256, 0, stream>>>(Abuf, Bt1, parts1, 25088, 98);
  reduce_fc1_kernel<<<1024, 256, 0, stream>>>(parts1, fc1_b, h1b);

  // fc2: (1024x1024) x (1024x1024)
  transpose_bf16_kernel<<<dim3(16, 16), 256, 0, stream>>>(fc2_w, Bt2, 1024, 1024);
  gemm_bt_kernel<<<dim3(8, 8, 2), 256, 0, stream>>>(h1b, Bt2, parts2, 1024, 16);
  reduce_fc2_kernel<<<1024, 256, 0, stream>>>(parts2, fc2_b, h2);

  // heads + final boxes/scores
  heads_kernel<<<1000, 64, 0, stream>>>(h2, cls_w, cls_b, bbox_w, bbox_b, rois, outp);
}

// Round 2
// 901.261 us; speedup vs baseline: 1.0993x; 1.0993x over previous
//
#include <hip/hip_runtime.h>
#include <cstdint>
#include <cstddef>

// ---------------------------------------------------------------------------
// Faster-RCNN forward, MI355X (gfx950).
// fp32 everywhere except: feat(NHWC) / roi-features(A) / fc1_w / fc2_w / h1
// which are bf16 for the MFMA GEMMs. RPN->topk path is pure fp32 so the
// top-1000 ordering matches the numpy reference.
// fc1 contraction uses permuted K-order k = p*512 + c (both A and B sides)
// so roi_align writes and transpose writes are coalesced.
// ---------------------------------------------------------------------------

typedef float  f4  __attribute__((ext_vector_type(4)));
typedef short  s8v __attribute__((ext_vector_type(8)));

__device__ __forceinline__ unsigned short f2bf(float f) {
  unsigned int u = __builtin_bit_cast(unsigned int, f);
  u += 0x7FFFu + ((u >> 16) & 1u);           // RNE
  return (unsigned short)(u >> 16);
}
__device__ __forceinline__ float bf2f(unsigned short h) {
  unsigned int u = ((unsigned int)h) << 16;
  return __builtin_bit_cast(float, u);
}

#define BBOX_CLAMP_F 4.135166556742356f

// ------------------------------ conv0: 3->64, 7x7, s2, p3, fused norm+ReLU --
__global__ __launch_bounds__(256, 2) void conv0_kernel(
    const float* __restrict__ img, const float* __restrict__ w,
    const float* __restrict__ bias, float* __restrict__ out) {
  __shared__ float patch[3][37][40];
  __shared__ float wlds[64][3][7][8];
  const int tid = threadIdx.x;
  const int tx0 = blockIdx.x * 16, ty0 = blockIdx.y * 16;
  for (int idx = tid; idx < 3 * 37 * 40; idx += 256) {
    int c = idx / 1480; int rem = idx - c * 1480; int r = rem / 40; int col = rem - r * 40;
    float v = 0.f;
    int iy = ty0 * 2 - 3 + r, ix = tx0 * 2 - 3 + col;
    if (col < 37 && iy >= 0 && iy < 512 && ix >= 0 && ix < 512) {
      float mval = (c == 0) ? 0.485f : (c == 1) ? 0.456f : 0.406f;
      float sval = (c == 0) ? 0.229f : (c == 1) ? 0.224f : 0.225f;
      v = (img[c * 262144 + iy * 512 + ix] - mval) / sval;
    }
    (&patch[0][0][0])[idx] = v;
  }
  for (int idx = tid; idx < 64 * 3 * 7 * 8; idx += 256) {
    int oc = idx / 168; int rem = idx - oc * 168; int c = rem / 56;
    int rem2 = rem - c * 56; int ky = rem2 >> 3; int kx = rem2 & 7;
    (&wlds[0][0][0][0])[idx] = (kx < 7) ? w[oc * 147 + c * 49 + ky * 7 + kx] : 0.f;
  }
  __syncthreads();
  const int ocg = tid >> 5, cell = tid & 31;
  const int cx = cell & 3, cy = cell >> 2;
  float acc[8][2][4] = {};
  for (int c = 0; c < 3; ++c) {
    for (int ky = 0; ky < 7; ++ky) {
      const float* p0 = &patch[c][cy * 4 + ky][cx * 8];
      const float* p1 = &patch[c][cy * 4 + ky + 2][cx * 8];
      f4 a0[4], a1[4];
      #pragma unroll
      for (int q = 0; q < 4; ++q) { a0[q] = *(const f4*)(p0 + q * 4); a1[q] = *(const f4*)(p1 + q * 4); }
      #pragma unroll
      for (int oc = 0; oc < 8; ++oc) {
        const float* wp = &wlds[ocg * 8 + oc][c][ky][0];
        f4 w0 = *(const f4*)wp, w1 = *(const f4*)(wp + 4);
        #pragma unroll
        for (int kx = 0; kx < 7; ++kx) {
          float wv = (kx < 4) ? w0[kx] : w1[kx - 4];
          #pragma unroll
          for (int x = 0; x < 4; ++x) {
            int e = x * 2 + kx;
            acc[oc][0][x] += a0[e >> 2][e & 3] * wv;
            acc[oc][1][x] += a1[e >> 2][e & 3] * wv;
          }
        }
      }
    }
  }
  #pragma unroll
  for (int oc = 0; oc < 8; ++oc) {
    float b = bias[ocg * 8 + oc];
    #pragma unroll
    for (int r = 0; r < 2; ++r) {
      f4 v;
      #pragma unroll
      for (int x = 0; x < 4; ++x) v[x] = fmaxf(acc[oc][r][x] + b, 0.f);
      *(f4*)&out[(size_t)(ocg * 8 + oc) * 65536 + (size_t)(ty0 + cy * 2 + r) * 256 + tx0 + cx * 4] = v;
    }
  }
}

// ------------------------------ maxpool 3x3 s2 p1: 64x256x256 -> 64x128x128 -
__global__ __launch_bounds__(256) void maxpool_kernel(
    const float* __restrict__ in, float* __restrict__ out) {
  int i = blockIdx.x * 256 + threadIdx.x;           // 64*128*128
  int c = i >> 14; int y = (i >> 7) & 127; int x = i & 127;
  float m = -INFINITY;
  #pragma unroll
  for (int dy = 0; dy < 3; ++dy) {
    int yy = 2 * y - 1 + dy;
    if (yy < 0 || yy >= 256) continue;
    #pragma unroll
    for (int dx = 0; dx < 3; ++dx) {
      int xx = 2 * x - 1 + dx;
      if (xx < 0 || xx >= 256) continue;
      m = fmaxf(m, in[c * 65536 + yy * 256 + xx]);
    }
  }
  out[i] = m;
}

// ------------------------------ generic 3x3 conv (partials over c-split) ----
template<int CIN, int COUT, int HIN, int HOUT, int STR, int TILES_X>
__global__ __launch_bounds__(256, 2) void conv3x3_kernel(
    const float* __restrict__ in, const float* __restrict__ w,
    float* __restrict__ parts) {
  constexpr int TW = 16, TH = 16;
  constexpr int SPAN  = (TH - 1) * STR + 3;
  constexpr int SPANW = (TW - 1) * STR + 3;
  constexpr int PADW  = (SPANW + 3) & ~3;
  constexpr int CSPL  = 32;
  __shared__ float patch[8][SPAN][PADW];
  __shared__ float wlds[32][8][3][4];
  const int tid = threadIdx.x;
  const int tile = blockIdx.x;
  const int tx0 = (tile % TILES_X) * TW, ty0 = (tile / TILES_X) * TH;
  const int ocb = blockIdx.y * 32;
  const int cb0 = blockIdx.z * CSPL;
  const int ocg = tid >> 5, cell = tid & 31;
  const int cx = cell & 3, cy = cell >> 2;
  float acc[4][2][4] = {};
  for (int cc = 0; cc < CSPL / 8; ++cc) {
    int cbase = cb0 + cc * 8;
    __syncthreads();
    for (int idx = tid; idx < 8 * SPAN * PADW; idx += 256) {
      int ch = idx / (SPAN * PADW);
      int rem = idx - ch * (SPAN * PADW);
      int r = rem / PADW;
      int col = rem - r * PADW;
      float v = 0.f;
      int iy = ty0 * STR - 1 + r, ix = tx0 * STR - 1 + col;
      if (col < SPANW && iy >= 0 && iy < HIN && ix >= 0 && ix < HIN)
        v = in[(size_t)(cbase + ch) * (HIN * HIN) + iy * HIN + ix];
      (&patch[0][0][0])[idx] = v;
    }
    for (int idx = tid; idx < 32 * 8 * 3 * 4; idx += 256) {
      int oc = idx / 96;
      int rem = idx - oc * 96;
      int ch = rem / 12;
      int rem2 = rem - ch * 12;
      int ky = rem2 >> 2, kx = rem2 & 3;
      (&wlds[0][0][0][0])[idx] = (kx < 3)
        ? w[((size_t)(ocb + oc) * CIN + cbase + ch) * 9 + ky * 3 + kx] : 0.f;
    }
    __syncthreads();
    #pragma unroll 1
    for (int ch = 0; ch < 8; ++ch) {
      #pragma unroll
      for (int ky = 0; ky < 3; ++ky) {
        constexpr int NF = (STR == 2) ? 3 : 2;
        const float* p0 = &patch[ch][(cy * 2 + 0) * STR + ky][cx * 4 * STR];
        const float* p1 = &patch[ch][(cy * 2 + 1) * STR + ky][cx * 4 * STR];
        f4 a0[NF], a1[NF];
        #pragma unroll
        for (int q = 0; q < NF; ++q) { a0[q] = *(const f4*)(p0 + q * 4); a1[q] = *(const f4*)(p1 + q * 4); }
        #pragma unroll
        for (int oc = 0; oc < 4; ++oc) {
          f4 wv = *(const f4*)&wlds[ocg * 4 + oc][ch][ky][0];
          #pragma unroll
          for (int kx = 0; kx < 3; ++kx) {
            #pragma unroll
            for (int x = 0; x < 4; ++x) {
              int e = x * STR + kx;
              acc[oc][0][x] += a0[e >> 2][e & 3] * wv[kx];
              acc[oc][1][x] += a1[e >> 2][e & 3] * wv[kx];
            }
          }
        }
      }
    }
  }
  size_t zb = (size_t)blockIdx.z * COUT * HOUT * HOUT;
  #pragma unroll
  for (int oc = 0; oc < 4; ++oc) {
    #pragma unroll
    for (int r = 0; r < 2; ++r) {
      f4 v;
      #pragma unroll
      for (int x = 0; x < 4; ++x) v[x] = acc[oc][r][x];
      *(f4*)&parts[zb + (size_t)(ocb + ocg * 4 + oc) * (HOUT * HOUT)
                   + (size_t)(ty0 + cy * 2 + r) * HOUT + tx0 + cx * 4] = v;
    }
  }
}

// -------- partial-sum + bias + relu (+ optional bf16 NHWC and fp32 NHWC) ----
template<int NS>
__global__ __launch_bounds__(256) void reduce_conv_kernel(
    const float* __restrict__ parts, const float* __restrict__ bias,
    float* __restrict__ out, int total, int hwshift,
    unsigned short* __restrict__ nhwc, float* __restrict__ nhwc32, int C) {
  int i = blockIdx.x * 256 + threadIdx.x;
  if (i >= total) return;
  float s = 0.f;
  #pragma unroll
  for (int k = 0; k < NS; ++k) s += parts[(size_t)k * total + i];
  int c = i >> hwshift;
  s += bias[c];
  s = fmaxf(s, 0.f);
  out[i] = s;
  int hw = 1 << hwshift;
  int px = i & (hw - 1);
  if (nhwc)   nhwc[(size_t)px * C + c] = f2bf(s);
  if (nhwc32) nhwc32[(size_t)px * C + c] = s;
}

// ------------------------------ RPN 1x1 heads (reads t in NHWC fp32) -------
__global__ __launch_bounds__(64) void rpn_head_kernel(
    const float* __restrict__ tn, const float* __restrict__ wc,
    const float* __restrict__ bc, const float* __restrict__ wb,
    const float* __restrict__ bb, float* __restrict__ objf,
    float* __restrict__ bdf) {
  int px = blockIdx.x, lane = threadIdx.x;
  float acc[45] = {};
  for (int j = 0; j < 8; ++j) {
    int c = j * 64 + lane;
    float tv = tn[px * 512 + c];
    #pragma unroll
    for (int a = 0; a < 9; ++a) acc[a] += tv * wc[a * 512 + c];
    #pragma unroll
    for (int o = 0; o < 36; ++o) acc[9 + o] += tv * wb[o * 512 + c];
  }
  #pragma unroll
  for (int o = 0; o < 45; ++o) {
    #pragma unroll
    for (int m = 32; m; m >>= 1) acc[o] += __shfl_xor(acc[o], m);
  }
  if (lane == 0) {
    #pragma unroll
    for (int a = 0; a < 9; ++a) objf[px * 9 + a] = acc[a] + bc[a];
    #pragma unroll
    for (int a = 0; a < 9; ++a)
      #pragma unroll
      for (int q = 0; q < 4; ++q)
        bdf[(px * 9 + a) * 4 + q] = acc[9 + a * 4 + q] + bb[a * 4 + q];
  }
}

// ------------------------------ anchor decode -> props (pre-clipped) -------
__device__ const float g_W2[9] = {91.f, 181.f, 362.f, 64.f, 128.f, 256.f, 45.f, 91.f, 181.f};
__device__ const float g_H2[9] = {45.f, 91.f, 181.f, 64.f, 128.f, 256.f, 91.f, 181.f, 362.f};

__global__ __launch_bounds__(256) void props_kernel(
    const float* __restrict__ bdf, float* __restrict__ props) {
  int i = blockIdx.x * 256 + threadIdx.x;
  if (i >= 2304) return;
  int pix = i / 9; int a = i - pix * 9;
  int y = pix >> 4, x = pix & 15;
  float wid = 2.f * g_W2[a], hei = 2.f * g_H2[a];
  float cx = (float)(x * 32), cy = (float)(y * 32);
  float dx = bdf[i * 4 + 0], dy = bdf[i * 4 + 1];
  float dw = fminf(bdf[i * 4 + 2], BBOX_CLAMP_F);
  float dh = fminf(bdf[i * 4 + 3], BBOX_CLAMP_F);
  float pcx = dx * wid + cx, pcy = dy * hei + cy;
  float pw = expf(dw) * wid, ph = expf(dh) * hei;
  props[i * 4 + 0] = fminf(fmaxf(pcx - 0.5f * pw, 0.f), 512.f);
  props[i * 4 + 1] = fminf(fmaxf(pcy - 0.5f * ph, 0.f), 512.f);
  props[i * 4 + 2] = fminf(fmaxf(pcx + 0.5f * pw, 0.f), 512.f);
  props[i * 4 + 3] = fminf(fmaxf(pcy + 0.5f * ph, 0.f), 512.f);
}

// ------------------------------ exact stable top-1000 by rank --------------
__global__ __launch_bounds__(256) void topk_kernel(
    const float* __restrict__ objf, const float* __restrict__ props,
    float* __restrict__ rois) {
  __shared__ float v[2304];
  int tid = threadIdx.x;
  for (int idx = tid; idx < 2304; idx += 256) v[idx] = objf[idx];
  __syncthreads();
  int i = blockIdx.x * 256 + tid;
  float vi = v[i];
  int rank = 0;
  for (int j = 0; j < 2304; ++j) {
    float vj = v[j];
    rank += (vj > vi) || (vj == vi && j < i);
  }
  if (rank < 1000) {
    f4 p = *(const f4*)(props + i * 4);
    *(f4*)(rois + rank * 4) = p;
  }
}

// ---------------- ROI-align -> A (bf16, k = p*512 + c), coalesced ----------
// 256 threads, 2 channels/thread via u32; writes A[m][p*512+c] contiguous.
__global__ __launch_bounds__(256) void roi_align_kernel(
    const float* __restrict__ rois, const unsigned short* __restrict__ featn,
    unsigned short* __restrict__ A) {
  __shared__ int   pidx[49][16];   // u32-unit offsets: (y*16+x)*256
  __shared__ float pwg[49][16];
  int m = blockIdx.x, tid = threadIdx.x;
  if (tid < 49) {
    int qy = tid / 7, qx = tid - qy * 7;
    float x1 = rois[m * 4 + 0] * 0.03125f;
    float y1 = rois[m * 4 + 1] * 0.03125f;
    float x2 = rois[m * 4 + 2] * 0.03125f;
    float y2 = rois[m * 4 + 3] * 0.03125f;
    float rw = fmaxf(x2 - x1, 1.f), rh = fmaxf(y2 - y1, 1.f);
    float wsx[2][2]; int xsx[2][2];
    float wsy[2][2]; int ysy[2][2];
    #pragma unroll
    for (int s = 0; s < 2; ++s) {
      float gx = ((float)(2 * qx + s) + 0.5f) / 14.f;
      float px = fminf(fmaxf(x1 + gx * rw, 0.f), 15.f);
      int x0 = (int)floorf(px);
      int x1i = min(x0 + 1, 15);
      float lx = px - (float)x0;
      xsx[s][0] = x0; xsx[s][1] = x1i; wsx[s][0] = 1.f - lx; wsx[s][1] = lx;
      float gy = ((float)(2 * qy + s) + 0.5f) / 14.f;
      float py = fminf(fmaxf(y1 + gy * rh, 0.f), 15.f);
      int y0 = (int)floorf(py);
      int y1i = min(y0 + 1, 15);
      float ly = py - (float)y0;
      ysy[s][0] = y0; ysy[s][1] = y1i; wsy[s][0] = 1.f - ly; wsy[s][1] = ly;
    }
    int e = 0;
    #pragma unroll
    for (int sy = 0; sy < 2; ++sy)
      #pragma unroll
      for (int cyi = 0; cyi < 2; ++cyi)
        #pragma unroll
        for (int sx = 0; sx < 2; ++sx)
          #pragma unroll
          for (int cxi = 0; cxi < 2; ++cxi) {
            pwg[tid][e] = 0.25f * wsy[sy][cyi] * wsx[sx][cxi];
            pidx[tid][e] = (ysy[sy][cyi] * 16 + xsx[sx][cxi]) * 256;
            ++e;
          }
  }
  __syncthreads();
  const unsigned int* F2 = (const unsigned int*)featn;  // 2 channels per u32
  unsigned int* A2 = (unsigned int*)A;
  size_t base = (size_t)m * 12544 + tid;                // u32 units
  for (int p = 0; p < 49; ++p) {
    float a0 = 0.f, a1 = 0.f;
    #pragma unroll
    for (int e = 0; e < 16; ++e) {
      unsigned int u = F2[pidx[p][e] + tid];
      float wgt = pwg[p][e];
      a0 += wgt * bf2f((unsigned short)(u & 0xffffu));
      a1 += wgt * bf2f((unsigned short)(u >> 16));
    }
    A2[base + (size_t)p * 256] =
        (unsigned int)f2bf(a0) | ((unsigned int)f2bf(a1) << 16);
  }
}

// --------- fc1_w (25088,1024) fp32 -> Bt1 (1024,25088) bf16, k=p*512+c -----
__global__ __launch_bounds__(256) void transpose_fc1_kernel(
    const float* __restrict__ src, unsigned short* __restrict__ dst) {
  __shared__ float tile[64][65];
  int p = blockIdx.x;              // 0..48
  int c0 = blockIdx.y * 64;        // 0..511
  int n0 = blockIdx.z * 64;        // 0..1023
  int tid = threadIdx.x;
  int rr = tid >> 4, c4 = tid & 15;
  #pragma unroll
  for (int j = 0; j < 4; ++j) {
    int c = rr + j * 16;
    f4 v = *(const f4*)(src + (size_t)((c0 + c) * 49 + p) * 1024 + n0 + c4 * 4);
    tile[c][c4 * 4 + 0] = v[0]; tile[c][c4 * 4 + 1] = v[1];
    tile[c][c4 * 4 + 2] = v[2]; tile[c][c4 * 4 + 3] = v[3];
  }
  __syncthreads();
  int nl = tid >> 2;
  int kc = (tid & 3) * 16;
  unsigned int u[8];
  #pragma unroll
  for (int i = 0; i < 8; ++i) {
    unsigned int lo = f2bf(tile[kc + 2 * i][nl]);
    unsigned int hi = f2bf(tile[kc + 2 * i + 1][nl]);
    u[i] = lo | (hi << 16);
  }
  uint4* dp = (uint4*)(dst + (size_t)(n0 + nl) * 25088 + p * 512 + c0 + kc);
  dp[0] = make_uint4(u[0], u[1], u[2], u[3]);
  dp[1] = make_uint4(u[4], u[5], u[6], u[7]);
}

// ------------------------------ fp32 (K,N) -> bf16 (N,K) transpose ---------
__global__ __launch_bounds__(256) void transpose_bf16_kernel(
    const float* __restrict__ src, unsigned short* __restrict__ dst,
    int K, int N) {
  __shared__ float tile[64][65];
  int k0 = blockIdx.x * 64, n0 = blockIdx.y * 64;
  int tid = threadIdx.x;
  int rr = tid >> 4, c4 = tid & 15;
  #pragma unroll
  for (int j = 0; j < 4; ++j) {
    int r = rr + j * 16;
    f4 v = *(const f4*)(src + (size_t)(k0 + r) * N + n0 + c4 * 4);
    tile[r][c4 * 4 + 0] = v[0]; tile[r][c4 * 4 + 1] = v[1];
    tile[r][c4 * 4 + 2] = v[2]; tile[r][c4 * 4 + 3] = v[3];
  }
  __syncthreads();
  int nl = tid >> 2;
  int kc = (tid & 3) * 16;
  unsigned int u[8];
  #pragma unroll
  for (int i = 0; i < 8; ++i) {
    unsigned int lo = f2bf(tile[kc + 2 * i][nl]);
    unsigned int hi = f2bf(tile[kc + 2 * i + 1][nl]);
    u[i] = lo | (hi << 16);
  }
  uint4* dp = (uint4*)(dst + (size_t)(n0 + nl) * K + k0 + kc);
  dp[0] = make_uint4(u[0], u[1], u[2], u[3]);
  dp[1] = make_uint4(u[4], u[5], u[6], u[7]);
}

// ------------------------------ bf16 GEMM  C = A(MxK) * B^T(NxK), split-K --
__global__ __launch_bounds__(256, 2) void gemm_bt_kernel(
    const unsigned short* __restrict__ A, const unsigned short* __restrict__ B,
    float* __restrict__ parts, int K, int nsteps) {
  __shared__ unsigned short As[128 * 32];
  __shared__ unsigned short Bs[128 * 32];
  const int tid = threadIdx.x;
  const int lane = tid & 63, wave = tid >> 6;
  const int n0 = blockIdx.x * 128, m0 = blockIdx.y * 128, ks = blockIdx.z;
  const int kbase = ks * nsteps * 32;
  f4 acc[4][4] = {};
  const int wr = wave >> 1, wc = wave & 1;
  const int rsel = lane & 15, ksel = (lane >> 4) * 8;
  for (int s = 0; s < nsteps; ++s) {
    int kk = kbase + s * 32;
    #pragma unroll
    for (int j = 0; j < 2; ++j) {
      int c_ = j * 256 + tid;
      int row = c_ >> 2;
      int k8 = (c_ & 3) << 3;
      __builtin_amdgcn_global_load_lds(
          (const __attribute__((address_space(1))) void*)(A + (size_t)(m0 + row) * K + kk + k8),
          (__attribute__((address_space(3))) void*)(As + c_ * 8), 16, 0, 0);
      __builtin_amdgcn_global_load_lds(
          (const __attribute__((address_space(1))) void*)(B + (size_t)(n0 + row) * K + kk + k8),
          (__attribute__((address_space(3))) void*)(Bs + c_ * 8), 16, 0, 0);
    }
    __syncthreads();
    s8v af[4], bfr[4];
    #pragma unroll
    for (int m = 0; m < 4; ++m)
      af[m] = *(const s8v*)(As + (wr * 64 + m * 16 + rsel) * 32 + ksel);
    #pragma unroll
    for (int n = 0; n < 4; ++n)
      bfr[n] = *(const s8v*)(Bs + (wc * 64 + n * 16 + rsel) * 32 + ksel);
    #pragma unroll
    for (int m = 0; m < 4; ++m)
      #pragma unroll
      for (int n = 0; n < 4; ++n)
        acc[m][n] = __builtin_amdgcn_mfma_f32_16x16x32_bf16(af[m], bfr[n], acc[m][n], 0, 0, 0);
    __syncthreads();
  }
  float* outp = parts + (size_t)ks * 1048576;
  int rb = m0 + wr * 64 + ((lane >> 4) << 2);
  int cb = n0 + wc * 64 + (lane & 15);
  #pragma unroll
  for (int m = 0; m < 4; ++m)
    #pragma unroll
    for (int n = 0; n < 4; ++n)
      #pragma unroll
      for (int i = 0; i < 4; ++i)
        outp[(size_t)(rb + m * 16 + i) * 1024 + cb + n * 16] = acc[m][n][i];
}

// ------------------------------ GEMM reductions ----------------------------
__global__ __launch_bounds__(256) void reduce_fc1_kernel(
    const float* __restrict__ parts, const float* __restrict__ bias,
    unsigned short* __restrict__ h1b) {
  int i4 = blockIdx.x * 256 + threadIdx.x;        // 1024*1024/4
  const f4* p4 = (const f4*)parts;
  f4 s = {0.f, 0.f, 0.f, 0.f};
  #pragma unroll
  for (int k = 0; k < 8; ++k) s += p4[(size_t)k * 262144 + i4];
  f4 b = ((const f4*)bias)[i4 & 255];
  s += b;
  unsigned int lo = (unsigned int)f2bf(fmaxf(s[0], 0.f)) | ((unsigned int)f2bf(fmaxf(s[1], 0.f)) << 16);
  unsigned int hi = (unsigned int)f2bf(fmaxf(s[2], 0.f)) | ((unsigned int)f2bf(fmaxf(s[3], 0.f)) << 16);
  ((uint2*)h1b)[i4] = make_uint2(lo, hi);
}

__global__ __launch_bounds__(256) void reduce_fc2_kernel(
    const float* __restrict__ parts, const float* __restrict__ bias,
    float* __restrict__ h2) {
  int i4 = blockIdx.x * 256 + threadIdx.x;
  const f4* p4 = (const f4*)parts;
  f4 s = p4[i4] + p4[262144 + i4];
  f4 b = ((const f4*)bias)[i4 & 255];
  s += b;
  #pragma unroll
  for (int j = 0; j < 4; ++j) s[j] = fmaxf(s[j], 0.f);
  ((f4*)h2)[i4] = s;
}

// ------------------------------ final heads + softmax + decode -------------
// 4 waves; wave w owns outputs o = w*8..w*8+7 (30 used), lanes split K.
__global__ __launch_bounds__(256) void heads_kernel(
    const float* __restrict__ h2, const float* __restrict__ cw,
    const float* __restrict__ cb, const float* __restrict__ bw,
    const float* __restrict__ bb, const float* __restrict__ rois,
    float* __restrict__ outp) {
  int m = blockIdx.x, tid = threadIdx.x;
  int lane = tid & 63, wv = tid >> 6;
  __shared__ float vals[32];
  const float* hrow = h2 + (size_t)m * 1024;
  float acc[8] = {};
  for (int k = lane; k < 1024; k += 64) {
    float hv = hrow[k];
    #pragma unroll
    for (int j = 0; j < 8; ++j) {
      int o = wv * 8 + j;
      float wval = 0.f;
      if (o < 6) wval = cw[k * 6 + o];
      else if (o < 30) wval = bw[k * 24 + o - 6];
      acc[j] += hv * wval;
    }
  }
  #pragma unroll
  for (int j = 0; j < 8; ++j) {
    #pragma unroll
    for (int s = 32; s; s >>= 1) acc[j] += __shfl_xor(acc[j], s);
  }
  if (lane == 0) {
    #pragma unroll
    for (int j = 0; j < 8; ++j) {
      int o = wv * 8 + j;
      if (o < 6) vals[o] = acc[j] + cb[o];
      else if (o < 30) vals[o] = acc[j] + bb[o - 6];
    }
  }
  __syncthreads();
  if (tid < 5) {
    int cls = tid + 1;
    float mx = vals[0];
    #pragma unroll
    for (int o = 1; o < 6; ++o) mx = fmaxf(mx, vals[o]);
    float den = 0.f;
    #pragma unroll
    for (int o = 0; o < 6; ++o) den += expf(vals[o] - mx);
    float score = expf(vals[cls] - mx) / den;
    float x1 = rois[m * 4 + 0], y1 = rois[m * 4 + 1];
    float x2 = rois[m * 4 + 2], y2 = rois[m * 4 + 3];
    float w_ = x2 - x1, h_ = y2 - y1;
    float cxx = x1 + 0.5f * w_, cyy = y1 + 0.5f * h_;
    float dx = vals[6 + cls * 4 + 0] / 10.f;
    float dy = vals[6 + cls * 4 + 1] / 10.f;
    float dw = fminf(vals[6 + cls * 4 + 2] / 5.f, BBOX_CLAMP_F);
    float dh = fminf(vals[6 + cls * 4 + 3] / 5.f, BBOX_CLAMP_F);
    float pcx = dx * w_ + cxx, pcy = dy * h_ + cyy;
    float pw = expf(dw) * w_, ph = expf(dh) * h_;
    float* op = outp + m * 25 + tid * 5;
    op[0] = fminf(fmaxf(pcx - 0.5f * pw, 0.f), 512.f);
    op[1] = fminf(fmaxf(pcy - 0.5f * ph, 0.f), 512.f);
    op[2] = fminf(fmaxf(pcx + 0.5f * pw, 0.f), 512.f);
    op[3] = fminf(fmaxf(pcy + 0.5f * ph, 0.f), 512.f);
    op[4] = score;
  }
}

// ---------------------------------------------------------------------------
// workspace layout (bytes). Total ~140 MB with heavy overlap.
// ---------------------------------------------------------------------------
static constexpr size_t MB_ = 1024ull * 1024ull;
static constexpr size_t A_OFF      = 0;
static constexpr size_t CONV0_OFF  = 0;
static constexpr size_t POOL_OFF   = 17 * MB_;
static constexpr size_t C1_OFF     = 22 * MB_;
static constexpr size_t C2_OFF     = 25 * MB_;
static constexpr size_t CPARTS_OFF = 27 * MB_;
static constexpr size_t FEAT_OFF   = 52 * MB_;
static constexpr size_t FEATN_OFF  = FEAT_OFF + 524288;
static constexpr size_t T_OFF      = FEATN_OFF + 262144;
static constexpr size_t OBJF_OFF   = T_OFF + 524288;
static constexpr size_t BDF_OFF    = OBJF_OFF + 16384;
static constexpr size_t PROPS_OFF  = BDF_OFF + 40960;
static constexpr size_t ROIS_OFF   = PROPS_OFF + 40960;
static constexpr size_t TN_OFF     = ROIS_OFF + 16384;     // t NHWC fp32, 512KB
static constexpr size_t BT1_OFF    = 54 * MB_;
static constexpr size_t H1B_OFF    = BT1_OFF;              // after GEMM1
static constexpr size_t BT2_OFF    = BT1_OFF + 2 * MB_;
static constexpr size_t PARTS2_OFF = BT1_OFF + 4 * MB_;
static constexpr size_t H2_OFF     = BT1_OFF + 13 * MB_;
static constexpr size_t PARTS1_OFF = 106 * MB_;

extern "C" void kernel_launch(void* const* d_in, const int* in_sizes, int n_in,
                              void* d_out, int out_size, void* d_ws, size_t ws_size,
                              hipStream_t stream) {
  (void)in_sizes; (void)n_in; (void)out_size; (void)ws_size;
  const float* images     = (const float*)d_in[0];
  const float* c0_w       = (const float*)d_in[1];
  const float* c0_b       = (const float*)d_in[2];
  const float* c1_w       = (const float*)d_in[3];
  const float* c1_b       = (const float*)d_in[4];
  const float* c2_w       = (const float*)d_in[5];
  const float* c2_b       = (const float*)d_in[6];
  const float* c3_w       = (const float*)d_in[7];
  const float* c3_b       = (const float*)d_in[8];
  const float* rpn_conv_w = (const float*)d_in[9];
  const float* rpn_conv_b = (const float*)d_in[10];
  const float* rpn_cls_w  = (const float*)d_in[11];
  const float* rpn_cls_b  = (const float*)d_in[12];
  const float* rpn_bbox_w = (const float*)d_in[13];
  const float* rpn_bbox_b = (const float*)d_in[14];
  const float* fc1_w      = (const float*)d_in[15];
  const float* fc1_b      = (const float*)d_in[16];
  const float* fc2_w      = (const float*)d_in[17];
  const float* fc2_b      = (const float*)d_in[18];
  const float* cls_w      = (const float*)d_in[19];
  const float* cls_b      = (const float*)d_in[20];
  const float* bbox_w     = (const float*)d_in[21];
  const float* bbox_b     = (const float*)d_in[22];

  char* ws = (char*)d_ws;
  float* conv0  = (float*)(ws + CONV0_OFF);
  float* pool   = (float*)(ws + POOL_OFF);
  float* c1o    = (float*)(ws + C1_OFF);
  float* c2o    = (float*)(ws + C2_OFF);
  float* cparts = (float*)(ws + CPARTS_OFF);
  float* feat   = (float*)(ws + FEAT_OFF);
  unsigned short* featn = (unsigned short*)(ws + FEATN_OFF);
  float* tbuf   = (float*)(ws + T_OFF);
  float* objf   = (float*)(ws + OBJF_OFF);
  float* bdf    = (float*)(ws + BDF_OFF);
  float* props  = (float*)(ws + PROPS_OFF);
  float* rois   = (float*)(ws + ROIS_OFF);
  float* tn     = (float*)(ws + TN_OFF);
  unsigned short* Abuf = (unsigned short*)(ws + A_OFF);
  unsigned short* Bt1  = (unsigned short*)(ws + BT1_OFF);
  unsigned short* h1b  = (unsigned short*)(ws + H1B_OFF);
  unsigned short* Bt2  = (unsigned short*)(ws + BT2_OFF);
  float* parts1 = (float*)(ws + PARTS1_OFF);
  float* parts2 = (float*)(ws + PARTS2_OFF);
  float* h2     = (float*)(ws + H2_OFF);
  float* outp   = (float*)d_out;

  // backbone
  conv0_kernel<<<dim3(16, 16), 256, 0, stream>>>(images, c0_w, c0_b, conv0);
  maxpool_kernel<<<4096, 256, 0, stream>>>(conv0, pool);
  conv3x3_kernel<64, 128, 128, 64, 2, 4><<<dim3(16, 4, 2), 256, 0, stream>>>(pool, c1_w, cparts);
  reduce_conv_kernel<2><<<2048, 256, 0, stream>>>(cparts, c1_b, c1o, 524288, 12, nullptr, nullptr, 0);
  conv3x3_kernel<128, 256, 64, 32, 2, 2><<<dim3(4, 8, 4), 256, 0, stream>>>(c1o, c2_w, cparts);
  reduce_conv_kernel<4><<<1024, 256, 0, stream>>>(cparts, c2_b, c2o, 262144, 10, nullptr, nullptr, 0);
  conv3x3_kernel<256, 512, 32, 16, 2, 1><<<dim3(1, 16, 8), 256, 0, stream>>>(c2o, c3_w, cparts);
  reduce_conv_kernel<8><<<512, 256, 0, stream>>>(cparts, c3_b, feat, 131072, 8, featn, nullptr, 512);

  // RPN
  conv3x3_kernel<512, 512, 16, 16, 1, 1><<<dim3(1, 16, 16), 256, 0, stream>>>(feat, rpn_conv_w, cparts);
  reduce_conv_kernel<16><<<512, 256, 0, stream>>>(cparts, rpn_conv_b, tbuf, 131072, 8, nullptr, tn, 512);
  rpn_head_kernel<<<256, 64, 0, stream>>>(tn, rpn_cls_w, rpn_cls_b, rpn_bbox_w, rpn_bbox_b, objf, bdf);
  props_kernel<<<9, 256, 0, stream>>>(bdf, props);
  topk_kernel<<<9, 256, 0, stream>>>(objf, props, rois);

  // ROI features (A), pad rows 1000..1023 to zero
  hipMemsetAsync(ws + A_OFF + (size_t)1000 * 25088 * 2, 0, (size_t)24 * 25088 * 2, stream);
  roi_align_kernel<<<1000, 256, 0, stream>>>(rois, featn, Abuf);

  // fc1: (1024x25088) x (25088x1024), K permuted as p*512+c on both sides
  transpose_fc1_kernel<<<dim3(49, 8, 16), 256, 0, stream>>>(fc1_w, Bt1);
  gemm_bt_kernel<<<dim3(8, 8, 8), 256, 0, stream>>>(Abuf, Bt1, parts1, 25088, 98);
  reduce_fc1_kernel<<<1024, 256, 0, stream>>>(parts1, fc1_b, h1b);

  // fc2: (1024x1024) x (1024x1024)
  transpose_bf16_kernel<<<dim3(16, 16), 256, 0, stream>>>(fc2_w, Bt2, 1024, 1024);
  gemm_bt_kernel<<<dim3(8, 8, 2), 256, 0, stream>>>(h1b, Bt2, parts2, 1024, 16);
  reduce_fc2_kernel<<<1024, 256, 0, stream>>>(parts2, fc2_b, h2);

  // heads + final boxes/scores
  heads_kernel<<<1000, 256, 0, stream>>>(h2, cls_w, cls_b, bbox_w, bbox_b, rois, outp);
}

// Round 3
// 704.826 us; speedup vs baseline: 1.4057x; 1.2787x over previous
//
#include <hip/hip_runtime.h>
#include <cstdint>
#include <cstddef>

// ---------------------------------------------------------------------------
// Faster-RCNN forward, MI355X (gfx950).
// fp32 everywhere except: feat(NHWC) / roi-features(A) / fc1_w / fc2_w / h1
// which are bf16 for the MFMA GEMMs. RPN->topk path is pure fp32 so the
// top-1000 ordering matches the numpy reference.
// fc1 contraction uses permuted K-order k = p*512 + c (both A and B sides).
// Convs: split-CIN across grid.z (CSPL channels per block) for occupancy.
// ---------------------------------------------------------------------------

typedef float  f4  __attribute__((ext_vector_type(4)));
typedef short  s8v __attribute__((ext_vector_type(8)));

__device__ __forceinline__ unsigned short f2bf(float f) {
  unsigned int u = __builtin_bit_cast(unsigned int, f);
  u += 0x7FFFu + ((u >> 16) & 1u);           // RNE
  return (unsigned short)(u >> 16);
}
__device__ __forceinline__ float bf2f(unsigned short h) {
  unsigned int u = ((unsigned int)h) << 16;
  return __builtin_bit_cast(float, u);
}

#define BBOX_CLAMP_F 4.135166556742356f

// -------- conv0: 3->64, 7x7, s2, p3, fused norm+ReLU; oc split over grid.z --
__global__ __launch_bounds__(256, 2) void conv0_kernel(
    const float* __restrict__ img, const float* __restrict__ w,
    const float* __restrict__ bias, float* __restrict__ out) {
  __shared__ float patch[3][37][40];
  __shared__ float wlds[32][3][7][8];
  const int tid = threadIdx.x;
  const int tx0 = blockIdx.x * 16, ty0 = blockIdx.y * 16;
  const int ocb = blockIdx.z * 32;
  for (int idx = tid; idx < 3 * 37 * 40; idx += 256) {
    int c = idx / 1480; int rem = idx - c * 1480; int r = rem / 40; int col = rem - r * 40;
    float v = 0.f;
    int iy = ty0 * 2 - 3 + r, ix = tx0 * 2 - 3 + col;
    if (col < 37 && iy >= 0 && iy < 512 && ix >= 0 && ix < 512) {
      float mval = (c == 0) ? 0.485f : (c == 1) ? 0.456f : 0.406f;
      float sval = (c == 0) ? 0.229f : (c == 1) ? 0.224f : 0.225f;
      v = (img[c * 262144 + iy * 512 + ix] - mval) / sval;
    }
    (&patch[0][0][0])[idx] = v;
  }
  for (int idx = tid; idx < 32 * 3 * 7 * 8; idx += 256) {
    int oc = idx / 168; int rem = idx - oc * 168; int c = rem / 56;
    int rem2 = rem - c * 56; int ky = rem2 >> 3; int kx = rem2 & 7;
    (&wlds[0][0][0][0])[idx] = (kx < 7) ? w[(ocb + oc) * 147 + c * 49 + ky * 7 + kx] : 0.f;
  }
  __syncthreads();
  const int ocg = tid >> 5, cell = tid & 31;
  const int cx = cell & 3, cy = cell >> 2;
  float acc[4][2][4] = {};
  for (int c = 0; c < 3; ++c) {
    for (int ky = 0; ky < 7; ++ky) {
      const float* p0 = &patch[c][cy * 4 + ky][cx * 8];
      const float* p1 = &patch[c][cy * 4 + ky + 2][cx * 8];
      f4 a0[4], a1[4];
      #pragma unroll
      for (int q = 0; q < 4; ++q) { a0[q] = *(const f4*)(p0 + q * 4); a1[q] = *(const f4*)(p1 + q * 4); }
      #pragma unroll
      for (int oc = 0; oc < 4; ++oc) {
        const float* wp = &wlds[ocg * 4 + oc][c][ky][0];
        f4 w0 = *(const f4*)wp, w1 = *(const f4*)(wp + 4);
        #pragma unroll
        for (int kx = 0; kx < 7; ++kx) {
          float wv = (kx < 4) ? w0[kx] : w1[kx - 4];
          #pragma unroll
          for (int x = 0; x < 4; ++x) {
            int e = x * 2 + kx;
            acc[oc][0][x] += a0[e >> 2][e & 3] * wv;
            acc[oc][1][x] += a1[e >> 2][e & 3] * wv;
          }
        }
      }
    }
  }
  #pragma unroll
  for (int oc = 0; oc < 4; ++oc) {
    float b = bias[ocb + ocg * 4 + oc];
    #pragma unroll
    for (int r = 0; r < 2; ++r) {
      f4 v;
      #pragma unroll
      for (int x = 0; x < 4; ++x) v[x] = fmaxf(acc[oc][r][x] + b, 0.f);
      *(f4*)&out[(size_t)(ocb + ocg * 4 + oc) * 65536 + (size_t)(ty0 + cy * 2 + r) * 256 + tx0 + cx * 4] = v;
    }
  }
}

// ------------------------------ maxpool 3x3 s2 p1: 64x256x256 -> 64x128x128 -
__global__ __launch_bounds__(256) void maxpool_kernel(
    const float* __restrict__ in, float* __restrict__ out) {
  int i = blockIdx.x * 256 + threadIdx.x;           // 64*128*128
  int c = i >> 14; int y = (i >> 7) & 127; int x = i & 127;
  float m = -INFINITY;
  #pragma unroll
  for (int dy = 0; dy < 3; ++dy) {
    int yy = 2 * y - 1 + dy;
    if (yy < 0 || yy >= 256) continue;
    #pragma unroll
    for (int dx = 0; dx < 3; ++dx) {
      int xx = 2 * x - 1 + dx;
      if (xx < 0 || xx >= 256) continue;
      m = fmaxf(m, in[c * 65536 + yy * 256 + xx]);
    }
  }
  out[i] = m;
}

// ------- generic 3x3 conv; grid = (tiles, COUT/32, CIN/CSPL) partials -------
template<int CIN, int COUT, int HIN, int HOUT, int STR, int TILES_X, int CSPL>
__global__ __launch_bounds__(256, 2) void conv3x3_kernel(
    const float* __restrict__ in, const float* __restrict__ w,
    float* __restrict__ parts) {
  constexpr int TW = 16, TH = 16;
  constexpr int SPAN  = (TH - 1) * STR + 3;
  constexpr int SPANW = (TW - 1) * STR + 3;
  constexpr int PADW  = (SPANW + 3) & ~3;
  __shared__ float patch[8][SPAN][PADW];
  __shared__ float wlds[32][8][3][4];
  const int tid = threadIdx.x;
  const int tile = blockIdx.x;
  const int tx0 = (tile % TILES_X) * TW, ty0 = (tile / TILES_X) * TH;
  const int ocb = blockIdx.y * 32;
  const int cb0 = blockIdx.z * CSPL;
  const int ocg = tid >> 5, cell = tid & 31;
  const int cx = cell & 3, cy = cell >> 2;
  float acc[4][2][4] = {};
  for (int cc = 0; cc < CSPL / 8; ++cc) {
    int cbase = cb0 + cc * 8;
    __syncthreads();
    for (int idx = tid; idx < 8 * SPAN * PADW; idx += 256) {
      int ch = idx / (SPAN * PADW);
      int rem = idx - ch * (SPAN * PADW);
      int r = rem / PADW;
      int col = rem - r * PADW;
      float v = 0.f;
      int iy = ty0 * STR - 1 + r, ix = tx0 * STR - 1 + col;
      if (col < SPANW && iy >= 0 && iy < HIN && ix >= 0 && ix < HIN)
        v = in[(size_t)(cbase + ch) * (HIN * HIN) + iy * HIN + ix];
      (&patch[0][0][0])[idx] = v;
    }
    for (int idx = tid; idx < 32 * 8 * 3 * 4; idx += 256) {
      int oc = idx / 96;
      int rem = idx - oc * 96;
      int ch = rem / 12;
      int rem2 = rem - ch * 12;
      int ky = rem2 >> 2, kx = rem2 & 3;
      (&wlds[0][0][0][0])[idx] = (kx < 3)
        ? w[((size_t)(ocb + oc) * CIN + cbase + ch) * 9 + ky * 3 + kx] : 0.f;
    }
    __syncthreads();
    #pragma unroll 1
    for (int ch = 0; ch < 8; ++ch) {
      #pragma unroll
      for (int ky = 0; ky < 3; ++ky) {
        constexpr int NF = (STR == 2) ? 3 : 2;
        const float* p0 = &patch[ch][(cy * 2 + 0) * STR + ky][cx * 4 * STR];
        const float* p1 = &patch[ch][(cy * 2 + 1) * STR + ky][cx * 4 * STR];
        f4 a0[NF], a1[NF];
        #pragma unroll
        for (int q = 0; q < NF; ++q) { a0[q] = *(const f4*)(p0 + q * 4); a1[q] = *(const f4*)(p1 + q * 4); }
        #pragma unroll
        for (int oc = 0; oc < 4; ++oc) {
          f4 wv = *(const f4*)&wlds[ocg * 4 + oc][ch][ky][0];
          #pragma unroll
          for (int kx = 0; kx < 3; ++kx) {
            #pragma unroll
            for (int x = 0; x < 4; ++x) {
              int e = x * STR + kx;
              acc[oc][0][x] += a0[e >> 2][e & 3] * wv[kx];
              acc[oc][1][x] += a1[e >> 2][e & 3] * wv[kx];
            }
          }
        }
      }
    }
  }
  size_t zb = (size_t)blockIdx.z * COUT * HOUT * HOUT;
  #pragma unroll
  for (int oc = 0; oc < 4; ++oc) {
    #pragma unroll
    for (int r = 0; r < 2; ++r) {
      f4 v;
      #pragma unroll
      for (int x = 0; x < 4; ++x) v[x] = acc[oc][r][x];
      *(f4*)&parts[zb + (size_t)(ocb + ocg * 4 + oc) * (HOUT * HOUT)
                   + (size_t)(ty0 + cy * 2 + r) * HOUT + tx0 + cx * 4] = v;
    }
  }
}

// ---- partial-sum + bias + relu, f4-vectorized (+ optional NHWC emits) ------
template<int NS>
__global__ __launch_bounds__(256) void reduce_conv_kernel(
    const float* __restrict__ parts, const float* __restrict__ bias,
    float* __restrict__ out, int total4, int hwshift,
    unsigned short* __restrict__ nhwc, float* __restrict__ nhwc32, int C) {
  int i4 = blockIdx.x * 256 + threadIdx.x;
  if (i4 >= total4) return;
  const f4* p4 = (const f4*)parts;
  f4 s = {0.f, 0.f, 0.f, 0.f};
  #pragma unroll
  for (int k = 0; k < NS; ++k) s += p4[(size_t)k * total4 + i4];
  int i = i4 * 4;
  int c = i >> hwshift;
  float b = bias[c];
  #pragma unroll
  for (int j = 0; j < 4; ++j) s[j] = fmaxf(s[j] + b, 0.f);
  ((f4*)out)[i4] = s;
  int hw = 1 << hwshift;
  int px = i & (hw - 1);
  if (nhwc) {
    #pragma unroll
    for (int j = 0; j < 4; ++j) nhwc[(size_t)(px + j) * C + c] = f2bf(s[j]);
  }
  if (nhwc32) {
    #pragma unroll
    for (int j = 0; j < 4; ++j) nhwc32[(size_t)(px + j) * C + c] = s[j];
  }
}

// ------------------------------ RPN 1x1 heads (reads t in NHWC fp32) -------
__global__ __launch_bounds__(64) void rpn_head_kernel(
    const float* __restrict__ tn, const float* __restrict__ wc,
    const float* __restrict__ bc, const float* __restrict__ wb,
    const float* __restrict__ bb, float* __restrict__ objf,
    float* __restrict__ bdf) {
  int px = blockIdx.x, lane = threadIdx.x;
  float acc[45] = {};
  for (int j = 0; j < 8; ++j) {
    int c = j * 64 + lane;
    float tv = tn[px * 512 + c];
    #pragma unroll
    for (int a = 0; a < 9; ++a) acc[a] += tv * wc[a * 512 + c];
    #pragma unroll
    for (int o = 0; o < 36; ++o) acc[9 + o] += tv * wb[o * 512 + c];
  }
  #pragma unroll
  for (int o = 0; o < 45; ++o) {
    #pragma unroll
    for (int m = 32; m; m >>= 1) acc[o] += __shfl_xor(acc[o], m);
  }
  if (lane == 0) {
    #pragma unroll
    for (int a = 0; a < 9; ++a) objf[px * 9 + a] = acc[a] + bc[a];
    #pragma unroll
    for (int a = 0; a < 9; ++a)
      #pragma unroll
      for (int q = 0; q < 4; ++q)
        bdf[(px * 9 + a) * 4 + q] = acc[9 + a * 4 + q] + bb[a * 4 + q];
  }
}

// ------------------------------ anchor decode -> props (pre-clipped) -------
__device__ const float g_W2[9] = {91.f, 181.f, 362.f, 64.f, 128.f, 256.f, 45.f, 91.f, 181.f};
__device__ const float g_H2[9] = {45.f, 91.f, 181.f, 64.f, 128.f, 256.f, 91.f, 181.f, 362.f};

__global__ __launch_bounds__(256) void props_kernel(
    const float* __restrict__ bdf, float* __restrict__ props) {
  int i = blockIdx.x * 256 + threadIdx.x;
  if (i >= 2304) return;
  int pix = i / 9; int a = i - pix * 9;
  int y = pix >> 4, x = pix & 15;
  float wid = 2.f * g_W2[a], hei = 2.f * g_H2[a];
  float cx = (float)(x * 32), cy = (float)(y * 32);
  float dx = bdf[i * 4 + 0], dy = bdf[i * 4 + 1];
  float dw = fminf(bdf[i * 4 + 2], BBOX_CLAMP_F);
  float dh = fminf(bdf[i * 4 + 3], BBOX_CLAMP_F);
  float pcx = dx * wid + cx, pcy = dy * hei + cy;
  float pw = expf(dw) * wid, ph = expf(dh) * hei;
  props[i * 4 + 0] = fminf(fmaxf(pcx - 0.5f * pw, 0.f), 512.f);
  props[i * 4 + 1] = fminf(fmaxf(pcy - 0.5f * ph, 0.f), 512.f);
  props[i * 4 + 2] = fminf(fmaxf(pcx + 0.5f * pw, 0.f), 512.f);
  props[i * 4 + 3] = fminf(fmaxf(pcy + 0.5f * ph, 0.f), 512.f);
}

// ------------------------------ exact stable top-1000 by rank --------------
__global__ __launch_bounds__(256) void topk_kernel(
    const float* __restrict__ objf, const float* __restrict__ props,
    float* __restrict__ rois) {
  __shared__ float v[2304];
  int tid = threadIdx.x;
  for (int idx = tid; idx < 2304; idx += 256) v[idx] = objf[idx];
  __syncthreads();
  int i = blockIdx.x * 256 + tid;
  float vi = v[i];
  int rank = 0;
  for (int j = 0; j < 2304; ++j) {
    float vj = v[j];
    rank += (vj > vi) || (vj == vi && j < i);
  }
  if (rank < 1000) {
    f4 p = *(const f4*)(props + i * 4);
    *(f4*)(rois + rank * 4) = p;
  }
}

// ---------------- ROI-align -> A (bf16, k = p*512 + c), coalesced ----------
__global__ __launch_bounds__(256) void roi_align_kernel(
    const float* __restrict__ rois, const unsigned short* __restrict__ featn,
    unsigned short* __restrict__ A) {
  __shared__ int   pidx[49][16];   // u32-unit offsets: (y*16+x)*256
  __shared__ float pwg[49][16];
  int m = blockIdx.x, tid = threadIdx.x;
  if (tid < 49) {
    int qy = tid / 7, qx = tid - qy * 7;
    float x1 = rois[m * 4 + 0] * 0.03125f;
    float y1 = rois[m * 4 + 1] * 0.03125f;
    float x2 = rois[m * 4 + 2] * 0.03125f;
    float y2 = rois[m * 4 + 3] * 0.03125f;
    float rw = fmaxf(x2 - x1, 1.f), rh = fmaxf(y2 - y1, 1.f);
    float wsx[2][2]; int xsx[2][2];
    float wsy[2][2]; int ysy[2][2];
    #pragma unroll
    for (int s = 0; s < 2; ++s) {
      float gx = ((float)(2 * qx + s) + 0.5f) / 14.f;
      float px = fminf(fmaxf(x1 + gx * rw, 0.f), 15.f);
      int x0 = (int)floorf(px);
      int x1i = min(x0 + 1, 15);
      float lx = px - (float)x0;
      xsx[s][0] = x0; xsx[s][1] = x1i; wsx[s][0] = 1.f - lx; wsx[s][1] = lx;
      float gy = ((float)(2 * qy + s) + 0.5f) / 14.f;
      float py = fminf(fmaxf(y1 + gy * rh, 0.f), 15.f);
      int y0 = (int)floorf(py);
      int y1i = min(y0 + 1, 15);
      float ly = py - (float)y0;
      ysy[s][0] = y0; ysy[s][1] = y1i; wsy[s][0] = 1.f - ly; wsy[s][1] = ly;
    }
    int e = 0;
    #pragma unroll
    for (int sy = 0; sy < 2; ++sy)
      #pragma unroll
      for (int cyi = 0; cyi < 2; ++cyi)
        #pragma unroll
        for (int sx = 0; sx < 2; ++sx)
          #pragma unroll
          for (int cxi = 0; cxi < 2; ++cxi) {
            pwg[tid][e] = 0.25f * wsy[sy][cyi] * wsx[sx][cxi];
            pidx[tid][e] = (ysy[sy][cyi] * 16 + xsx[sx][cxi]) * 256;
            ++e;
          }
  }
  __syncthreads();
  const unsigned int* F2 = (const unsigned int*)featn;  // 2 channels per u32
  unsigned int* A2 = (unsigned int*)A;
  size_t base = (size_t)m * 12544 + tid;                // u32 units
  for (int p = 0; p < 49; ++p) {
    float a0 = 0.f, a1 = 0.f;
    #pragma unroll
    for (int e = 0; e < 16; ++e) {
      unsigned int u = F2[pidx[p][e] + tid];
      float wgt = pwg[p][e];
      a0 += wgt * bf2f((unsigned short)(u & 0xffffu));
      a1 += wgt * bf2f((unsigned short)(u >> 16));
    }
    A2[base + (size_t)p * 256] =
        (unsigned int)f2bf(a0) | ((unsigned int)f2bf(a1) << 16);
  }
}

// --------- fc1_w (25088,1024) fp32 -> Bt1 (1024,25088) bf16, k=p*512+c -----
__global__ __launch_bounds__(256) void transpose_fc1_kernel(
    const float* __restrict__ src, unsigned short* __restrict__ dst) {
  __shared__ float tile[64][65];
  int p = blockIdx.x;              // 0..48
  int c0 = blockIdx.y * 64;        // 0..511
  int n0 = blockIdx.z * 64;        // 0..1023
  int tid = threadIdx.x;
  int rr = tid >> 4, c4 = tid & 15;
  #pragma unroll
  for (int j = 0; j < 4; ++j) {
    int c = rr + j * 16;
    f4 v = *(const f4*)(src + (size_t)((c0 + c) * 49 + p) * 1024 + n0 + c4 * 4);
    tile[c][c4 * 4 + 0] = v[0]; tile[c][c4 * 4 + 1] = v[1];
    tile[c][c4 * 4 + 2] = v[2]; tile[c][c4 * 4 + 3] = v[3];
  }
  __syncthreads();
  int nl = tid >> 2;
  int kc = (tid & 3) * 16;
  unsigned int u[8];
  #pragma unroll
  for (int i = 0; i < 8; ++i) {
    unsigned int lo = f2bf(tile[kc + 2 * i][nl]);
    unsigned int hi = f2bf(tile[kc + 2 * i + 1][nl]);
    u[i] = lo | (hi << 16);
  }
  uint4* dp = (uint4*)(dst + (size_t)(n0 + nl) * 25088 + p * 512 + c0 + kc);
  dp[0] = make_uint4(u[0], u[1], u[2], u[3]);
  dp[1] = make_uint4(u[4], u[5], u[6], u[7]);
}

// ------------------------------ fp32 (K,N) -> bf16 (N,K) transpose ---------
__global__ __launch_bounds__(256) void transpose_bf16_kernel(
    const float* __restrict__ src, unsigned short* __restrict__ dst,
    int K, int N) {
  __shared__ float tile[64][65];
  int k0 = blockIdx.x * 64, n0 = blockIdx.y * 64;
  int tid = threadIdx.x;
  int rr = tid >> 4, c4 = tid & 15;
  #pragma unroll
  for (int j = 0; j < 4; ++j) {
    int r = rr + j * 16;
    f4 v = *(const f4*)(src + (size_t)(k0 + r) * N + n0 + c4 * 4);
    tile[r][c4 * 4 + 0] = v[0]; tile[r][c4 * 4 + 1] = v[1];
    tile[r][c4 * 4 + 2] = v[2]; tile[r][c4 * 4 + 3] = v[3];
  }
  __syncthreads();
  int nl = tid >> 2;
  int kc = (tid & 3) * 16;
  unsigned int u[8];
  #pragma unroll
  for (int i = 0; i < 8; ++i) {
    unsigned int lo = f2bf(tile[kc + 2 * i][nl]);
    unsigned int hi = f2bf(tile[kc + 2 * i + 1][nl]);
    u[i] = lo | (hi << 16);
  }
  uint4* dp = (uint4*)(dst + (size_t)(n0 + nl) * K + k0 + kc);
  dp[0] = make_uint4(u[0], u[1], u[2], u[3]);
  dp[1] = make_uint4(u[4], u[5], u[6], u[7]);
}

// ------------------------------ bf16 GEMM  C = A(MxK) * B^T(NxK), split-K --
__global__ __launch_bounds__(256, 2) void gemm_bt_kernel(
    const unsigned short* __restrict__ A, const unsigned short* __restrict__ B,
    float* __restrict__ parts, int K, int nsteps) {
  __shared__ unsigned short As[128 * 32];
  __shared__ unsigned short Bs[128 * 32];
  const int tid = threadIdx.x;
  const int lane = tid & 63, wave = tid >> 6;
  const int n0 = blockIdx.x * 128, m0 = blockIdx.y * 128, ks = blockIdx.z;
  const int kbase = ks * nsteps * 32;
  f4 acc[4][4] = {};
  const int wr = wave >> 1, wc = wave & 1;
  const int rsel = lane & 15, ksel = (lane >> 4) * 8;
  for (int s = 0; s < nsteps; ++s) {
    int kk = kbase + s * 32;
    #pragma unroll
    for (int j = 0; j < 2; ++j) {
      int c_ = j * 256 + tid;
      int row = c_ >> 2;
      int k8 = (c_ & 3) << 3;
      __builtin_amdgcn_global_load_lds(
          (const __attribute__((address_space(1))) void*)(A + (size_t)(m0 + row) * K + kk + k8),
          (__attribute__((address_space(3))) void*)(As + c_ * 8), 16, 0, 0);
      __builtin_amdgcn_global_load_lds(
          (const __attribute__((address_space(1))) void*)(B + (size_t)(n0 + row) * K + kk + k8),
          (__attribute__((address_space(3))) void*)(Bs + c_ * 8), 16, 0, 0);
    }
    __syncthreads();
    s8v af[4], bfr[4];
    #pragma unroll
    for (int m = 0; m < 4; ++m)
      af[m] = *(const s8v*)(As + (wr * 64 + m * 16 + rsel) * 32 + ksel);
    #pragma unroll
    for (int n = 0; n < 4; ++n)
      bfr[n] = *(const s8v*)(Bs + (wc * 64 + n * 16 + rsel) * 32 + ksel);
    #pragma unroll
    for (int m = 0; m < 4; ++m)
      #pragma unroll
      for (int n = 0; n < 4; ++n)
        acc[m][n] = __builtin_amdgcn_mfma_f32_16x16x32_bf16(af[m], bfr[n], acc[m][n], 0, 0, 0);
    __syncthreads();
  }
  float* outp = parts + (size_t)ks * 1048576;
  int rb = m0 + wr * 64 + ((lane >> 4) << 2);
  int cb = n0 + wc * 64 + (lane & 15);
  #pragma unroll
  for (int m = 0; m < 4; ++m)
    #pragma unroll
    for (int n = 0; n < 4; ++n)
      #pragma unroll
      for (int i = 0; i < 4; ++i)
        outp[(size_t)(rb + m * 16 + i) * 1024 + cb + n * 16] = acc[m][n][i];
}

// ------------------------------ GEMM reductions ----------------------------
__global__ __launch_bounds__(256) void reduce_fc1_kernel(
    const float* __restrict__ parts, const float* __restrict__ bias,
    unsigned short* __restrict__ h1b) {
  int i4 = blockIdx.x * 256 + threadIdx.x;        // 1024*1024/4
  const f4* p4 = (const f4*)parts;
  f4 s = {0.f, 0.f, 0.f, 0.f};
  #pragma unroll
  for (int k = 0; k < 8; ++k) s += p4[(size_t)k * 262144 + i4];
  f4 b = ((const f4*)bias)[i4 & 255];
  s += b;
  unsigned int lo = (unsigned int)f2bf(fmaxf(s[0], 0.f)) | ((unsigned int)f2bf(fmaxf(s[1], 0.f)) << 16);
  unsigned int hi = (unsigned int)f2bf(fmaxf(s[2], 0.f)) | ((unsigned int)f2bf(fmaxf(s[3], 0.f)) << 16);
  ((uint2*)h1b)[i4] = make_uint2(lo, hi);
}

__global__ __launch_bounds__(256) void reduce_fc2_kernel(
    const float* __restrict__ parts, const float* __restrict__ bias,
    float* __restrict__ h2) {
  int i4 = blockIdx.x * 256 + threadIdx.x;
  const f4* p4 = (const f4*)parts;
  f4 s = p4[i4] + p4[262144 + i4];
  f4 b = ((const f4*)bias)[i4 & 255];
  s += b;
  #pragma unroll
  for (int j = 0; j < 4; ++j) s[j] = fmaxf(s[j], 0.f);
  ((f4*)h2)[i4] = s;
}

// ------------------------------ final heads + softmax + decode -------------
__global__ __launch_bounds__(256) void heads_kernel(
    const float* __restrict__ h2, const float* __restrict__ cw,
    const float* __restrict__ cb, const float* __restrict__ bw,
    const float* __restrict__ bb, const float* __restrict__ rois,
    float* __restrict__ outp) {
  int m = blockIdx.x, tid = threadIdx.x;
  int lane = tid & 63, wv = tid >> 6;
  __shared__ float vals[32];
  const float* hrow = h2 + (size_t)m * 1024;
  float acc[8] = {};
  for (int k = lane; k < 1024; k += 64) {
    float hv = hrow[k];
    #pragma unroll
    for (int j = 0; j < 8; ++j) {
      int o = wv * 8 + j;
      float wval = 0.f;
      if (o < 6) wval = cw[k * 6 + o];
      else if (o < 30) wval = bw[k * 24 + o - 6];
      acc[j] += hv * wval;
    }
  }
  #pragma unroll
  for (int j = 0; j < 8; ++j) {
    #pragma unroll
    for (int s = 32; s; s >>= 1) acc[j] += __shfl_xor(acc[j], s);
  }
  if (lane == 0) {
    #pragma unroll
    for (int j = 0; j < 8; ++j) {
      int o = wv * 8 + j;
      if (o < 6) vals[o] = acc[j] + cb[o];
      else if (o < 30) vals[o] = acc[j] + bb[o - 6];
    }
  }
  __syncthreads();
  if (tid < 5) {
    int cls = tid + 1;
    float mx = vals[0];
    #pragma unroll
    for (int o = 1; o < 6; ++o) mx = fmaxf(mx, vals[o]);
    float den = 0.f;
    #pragma unroll
    for (int o = 0; o < 6; ++o) den += expf(vals[o] - mx);
    float score = expf(vals[cls] - mx) / den;
    float x1 = rois[m * 4 + 0], y1 = rois[m * 4 + 1];
    float x2 = rois[m * 4 + 2], y2 = rois[m * 4 + 3];
    float w_ = x2 - x1, h_ = y2 - y1;
    float cxx = x1 + 0.5f * w_, cyy = y1 + 0.5f * h_;
    float dx = vals[6 + cls * 4 + 0] / 10.f;
    float dy = vals[6 + cls * 4 + 1] / 10.f;
    float dw = fminf(vals[6 + cls * 4 + 2] / 5.f, BBOX_CLAMP_F);
    float dh = fminf(vals[6 + cls * 4 + 3] / 5.f, BBOX_CLAMP_F);
    float pcx = dx * w_ + cxx, pcy = dy * h_ + cyy;
    float pw = expf(dw) * w_, ph = expf(dh) * h_;
    float* op = outp + m * 25 + tid * 5;
    op[0] = fminf(fmaxf(pcx - 0.5f * pw, 0.f), 512.f);
    op[1] = fminf(fmaxf(pcy - 0.5f * ph, 0.f), 512.f);
    op[2] = fminf(fmaxf(pcx + 0.5f * pw, 0.f), 512.f);
    op[3] = fminf(fmaxf(pcy + 0.5f * ph, 0.f), 512.f);
    op[4] = score;
  }
}

// ---------------------------------------------------------------------------
// workspace layout (bytes). Total ~140 MB with heavy overlap.
// ---------------------------------------------------------------------------
static constexpr size_t MB_ = 1024ull * 1024ull;
static constexpr size_t A_OFF      = 0;
static constexpr size_t CONV0_OFF  = 0;
static constexpr size_t POOL_OFF   = 17 * MB_;
static constexpr size_t C1_OFF     = 22 * MB_;
static constexpr size_t C2_OFF     = 25 * MB_;
static constexpr size_t CPARTS_OFF = 27 * MB_;   // up to 16 MB of partials
static constexpr size_t FEAT_OFF   = 52 * MB_;
static constexpr size_t FEATN_OFF  = FEAT_OFF + 524288;
static constexpr size_t T_OFF      = FEATN_OFF + 262144;
static constexpr size_t OBJF_OFF   = T_OFF + 524288;
static constexpr size_t BDF_OFF    = OBJF_OFF + 16384;
static constexpr size_t PROPS_OFF  = BDF_OFF + 40960;
static constexpr size_t ROIS_OFF   = PROPS_OFF + 40960;
static constexpr size_t TN_OFF     = ROIS_OFF + 16384;     // t NHWC fp32, 512KB
static constexpr size_t BT1_OFF    = 54 * MB_;
static constexpr size_t H1B_OFF    = BT1_OFF;              // after GEMM1
static constexpr size_t BT2_OFF    = BT1_OFF + 2 * MB_;
static constexpr size_t PARTS2_OFF = BT1_OFF + 4 * MB_;
static constexpr size_t H2_OFF     = BT1_OFF + 13 * MB_;
static constexpr size_t PARTS1_OFF = 106 * MB_;

extern "C" void kernel_launch(void* const* d_in, const int* in_sizes, int n_in,
                              void* d_out, int out_size, void* d_ws, size_t ws_size,
                              hipStream_t stream) {
  (void)in_sizes; (void)n_in; (void)out_size; (void)ws_size;
  const float* images     = (const float*)d_in[0];
  const float* c0_w       = (const float*)d_in[1];
  const float* c0_b       = (const float*)d_in[2];
  const float* c1_w       = (const float*)d_in[3];
  const float* c1_b       = (const float*)d_in[4];
  const float* c2_w       = (const float*)d_in[5];
  const float* c2_b       = (const float*)d_in[6];
  const float* c3_w       = (const float*)d_in[7];
  const float* c3_b       = (const float*)d_in[8];
  const float* rpn_conv_w = (const float*)d_in[9];
  const float* rpn_conv_b = (const float*)d_in[10];
  const float* rpn_cls_w  = (const float*)d_in[11];
  const float* rpn_cls_b  = (const float*)d_in[12];
  const float* rpn_bbox_w = (const float*)d_in[13];
  const float* rpn_bbox_b = (const float*)d_in[14];
  const float* fc1_w      = (const float*)d_in[15];
  const float* fc1_b      = (const float*)d_in[16];
  const float* fc2_w      = (const float*)d_in[17];
  const float* fc2_b      = (const float*)d_in[18];
  const float* cls_w      = (const float*)d_in[19];
  const float* cls_b      = (const float*)d_in[20];
  const float* bbox_w     = (const float*)d_in[21];
  const float* bbox_b     = (const float*)d_in[22];

  char* ws = (char*)d_ws;
  float* conv0  = (float*)(ws + CONV0_OFF);
  float* pool   = (float*)(ws + POOL_OFF);
  float* c1o    = (float*)(ws + C1_OFF);
  float* c2o    = (float*)(ws + C2_OFF);
  float* cparts = (float*)(ws + CPARTS_OFF);
  float* feat   = (float*)(ws + FEAT_OFF);
  unsigned short* featn = (unsigned short*)(ws + FEATN_OFF);
  float* tbuf   = (float*)(ws + T_OFF);
  float* objf   = (float*)(ws + OBJF_OFF);
  float* bdf    = (float*)(ws + BDF_OFF);
  float* props  = (float*)(ws + PROPS_OFF);
  float* rois   = (float*)(ws + ROIS_OFF);
  float* tn     = (float*)(ws + TN_OFF);
  unsigned short* Abuf = (unsigned short*)(ws + A_OFF);
  unsigned short* Bt1  = (unsigned short*)(ws + BT1_OFF);
  unsigned short* h1b  = (unsigned short*)(ws + H1B_OFF);
  unsigned short* Bt2  = (unsigned short*)(ws + BT2_OFF);
  float* parts1 = (float*)(ws + PARTS1_OFF);
  float* parts2 = (float*)(ws + PARTS2_OFF);
  float* h2     = (float*)(ws + H2_OFF);
  float* outp   = (float*)d_out;

  // backbone (convs split CIN over grid.z for occupancy)
  conv0_kernel<<<dim3(16, 16, 2), 256, 0, stream>>>(images, c0_w, c0_b, conv0);
  maxpool_kernel<<<4096, 256, 0, stream>>>(conv0, pool);
  conv3x3_kernel<64, 128, 128, 64, 2, 4, 8><<<dim3(16, 4, 8), 256, 0, stream>>>(pool, c1_w, cparts);
  reduce_conv_kernel<8><<<512, 256, 0, stream>>>(cparts, c1_b, c1o, 131072, 12, nullptr, nullptr, 0);
  conv3x3_kernel<128, 256, 64, 32, 2, 2, 8><<<dim3(4, 8, 16), 256, 0, stream>>>(c1o, c2_w, cparts);
  reduce_conv_kernel<16><<<256, 256, 0, stream>>>(cparts, c2_b, c2o, 65536, 10, nullptr, nullptr, 0);
  conv3x3_kernel<256, 512, 32, 16, 2, 1, 8><<<dim3(1, 16, 32), 256, 0, stream>>>(c2o, c3_w, cparts);
  reduce_conv_kernel<32><<<128, 256, 0, stream>>>(cparts, c3_b, feat, 32768, 8, featn, nullptr, 512);

  // RPN
  conv3x3_kernel<512, 512, 16, 16, 1, 1, 16><<<dim3(1, 16, 32), 256, 0, stream>>>(feat, rpn_conv_w, cparts);
  reduce_conv_kernel<32><<<128, 256, 0, stream>>>(cparts, rpn_conv_b, tbuf, 32768, 8, nullptr, tn, 512);
  rpn_head_kernel<<<256, 64, 0, stream>>>(tn, rpn_cls_w, rpn_cls_b, rpn_bbox_w, rpn_bbox_b, objf, bdf);
  props_kernel<<<9, 256, 0, stream>>>(bdf, props);
  topk_kernel<<<9, 256, 0, stream>>>(objf, props, rois);

  // ROI features (A), pad rows 1000..1023 to zero
  hipMemsetAsync(ws + A_OFF + (size_t)1000 * 25088 * 2, 0, (size_t)24 * 25088 * 2, stream);
  roi_align_kernel<<<1000, 256, 0, stream>>>(rois, featn, Abuf);

  // fc1: (1024x25088) x (25088x1024), K permuted as p*512+c on both sides
  transpose_fc1_kernel<<<dim3(49, 8, 16), 256, 0, stream>>>(fc1_w, Bt1);
  gemm_bt_kernel<<<dim3(8, 8, 8), 256, 0, stream>>>(Abuf, Bt1, parts1, 25088, 98);
  reduce_fc1_kernel<<<1024, 256, 0, stream>>>(parts1, fc1_b, h1b);

  // fc2: (1024x1024) x (1024x1024)
  transpose_bf16_kernel<<<dim3(16, 16), 256, 0, stream>>>(fc2_w, Bt2, 1024, 1024);
  gemm_bt_kernel<<<dim3(8, 8, 2), 256, 0, stream>>>(h1b, Bt2, parts2, 1024, 16);
  reduce_fc2_kernel<<<1024, 256, 0, stream>>>(parts2, fc2_b, h2);

  // heads + final boxes/scores
  heads_kernel<<<1000, 256, 0, stream>>>(h2, cls_w, cls_b, bbox_w, bbox_b, rois, outp);
}

// Round 4
// 691.734 us; speedup vs baseline: 1.4323x; 1.0189x over previous
//
#include <hip/hip_runtime.h>
#include <cstdint>
#include <cstddef>

// ---------------------------------------------------------------------------
// Faster-RCNN forward, MI355X (gfx950).
// fp32 everywhere except: feat(NHWC) / roi-features(A) / fc1_w / fc2_w / h1
// (+ fc1 split-K partials) which are bf16 for the MFMA GEMMs. RPN->topk path
// is pure fp32 so the top-1000 ordering matches the numpy reference.
// fc1 contraction uses permuted K-order k = p*512 + c (both A and B sides).
// ---------------------------------------------------------------------------

typedef float  f4  __attribute__((ext_vector_type(4)));
typedef short  s8v __attribute__((ext_vector_type(8)));

__device__ __forceinline__ unsigned short f2bf(float f) {
  unsigned int u = __builtin_bit_cast(unsigned int, f);
  u += 0x7FFFu + ((u >> 16) & 1u);           // RNE
  return (unsigned short)(u >> 16);
}
__device__ __forceinline__ float bf2f(unsigned short h) {
  unsigned int u = ((unsigned int)h) << 16;
  return __builtin_bit_cast(float, u);
}

#define BBOX_CLAMP_F 4.135166556742356f

// -------- conv0: 3->64, 7x7, s2, p3, fused norm+ReLU; oc split over grid.z --
__global__ __launch_bounds__(256, 2) void conv0_kernel(
    const float* __restrict__ img, const float* __restrict__ w,
    const float* __restrict__ bias, float* __restrict__ out) {
  __shared__ float patch[3][37][40];
  __shared__ float wlds[32][3][7][8];
  const int tid = threadIdx.x;
  const int tx0 = blockIdx.x * 16, ty0 = blockIdx.y * 16;
  const int ocb = blockIdx.z * 32;
  for (int idx = tid; idx < 3 * 37 * 40; idx += 256) {
    int c = idx / 1480; int rem = idx - c * 1480; int r = rem / 40; int col = rem - r * 40;
    float v = 0.f;
    int iy = ty0 * 2 - 3 + r, ix = tx0 * 2 - 3 + col;
    if (col < 37 && iy >= 0 && iy < 512 && ix >= 0 && ix < 512) {
      float mval = (c == 0) ? 0.485f : (c == 1) ? 0.456f : 0.406f;
      float sval = (c == 0) ? 0.229f : (c == 1) ? 0.224f : 0.225f;
      v = (img[c * 262144 + iy * 512 + ix] - mval) / sval;
    }
    (&patch[0][0][0])[idx] = v;
  }
  for (int idx = tid; idx < 32 * 3 * 7 * 8; idx += 256) {
    int oc = idx / 168; int rem = idx - oc * 168; int c = rem / 56;
    int rem2 = rem - c * 56; int ky = rem2 >> 3; int kx = rem2 & 7;
    (&wlds[0][0][0][0])[idx] = (kx < 7) ? w[(ocb + oc) * 147 + c * 49 + ky * 7 + kx] : 0.f;
  }
  __syncthreads();
  const int ocg = tid >> 5, cell = tid & 31;
  const int cx = cell & 3, cy = cell >> 2;
  float acc[4][2][4] = {};
  for (int c = 0; c < 3; ++c) {
    for (int ky = 0; ky < 7; ++ky) {
      const float* p0 = &patch[c][cy * 4 + ky][cx * 8];
      const float* p1 = &patch[c][cy * 4 + ky + 2][cx * 8];
      f4 a0[4], a1[4];
      #pragma unroll
      for (int q = 0; q < 4; ++q) { a0[q] = *(const f4*)(p0 + q * 4); a1[q] = *(const f4*)(p1 + q * 4); }
      #pragma unroll
      for (int oc = 0; oc < 4; ++oc) {
        const float* wp = &wlds[ocg * 4 + oc][c][ky][0];
        f4 w0 = *(const f4*)wp, w1 = *(const f4*)(wp + 4);
        #pragma unroll
        for (int kx = 0; kx < 7; ++kx) {
          float wv = (kx < 4) ? w0[kx] : w1[kx - 4];
          #pragma unroll
          for (int x = 0; x < 4; ++x) {
            int e = x * 2 + kx;
            acc[oc][0][x] += a0[e >> 2][e & 3] * wv;
            acc[oc][1][x] += a1[e >> 2][e & 3] * wv;
          }
        }
      }
    }
  }
  #pragma unroll
  for (int oc = 0; oc < 4; ++oc) {
    float b = bias[ocb + ocg * 4 + oc];
    #pragma unroll
    for (int r = 0; r < 2; ++r) {
      f4 v;
      #pragma unroll
      for (int x = 0; x < 4; ++x) v[x] = fmaxf(acc[oc][r][x] + b, 0.f);
      *(f4*)&out[(size_t)(ocb + ocg * 4 + oc) * 65536 + (size_t)(ty0 + cy * 2 + r) * 256 + tx0 + cx * 4] = v;
    }
  }
}

// ------------------------------ maxpool 3x3 s2 p1: 64x256x256 -> 64x128x128 -
__global__ __launch_bounds__(256) void maxpool_kernel(
    const float* __restrict__ in, float* __restrict__ out) {
  int i = blockIdx.x * 256 + threadIdx.x;           // 64*128*128
  int c = i >> 14; int y = (i >> 7) & 127; int x = i & 127;
  float m = -INFINITY;
  #pragma unroll
  for (int dy = 0; dy < 3; ++dy) {
    int yy = 2 * y - 1 + dy;
    if (yy < 0 || yy >= 256) continue;
    #pragma unroll
    for (int dx = 0; dx < 3; ++dx) {
      int xx = 2 * x - 1 + dx;
      if (xx < 0 || xx >= 256) continue;
      m = fmaxf(m, in[c * 65536 + yy * 256 + xx]);
    }
  }
  out[i] = m;
}

// ------- generic 3x3 conv; grid = (tiles, COUT/32, CIN/CSPL) partials -------
template<int CIN, int COUT, int HIN, int HOUT, int STR, int TILES_X, int CSPL>
__global__ __launch_bounds__(256, 2) void conv3x3_kernel(
    const float* __restrict__ in, const float* __restrict__ w,
    float* __restrict__ parts) {
  constexpr int TW = 16, TH = 16;
  constexpr int SPAN  = (TH - 1) * STR + 3;
  constexpr int SPANW = (TW - 1) * STR + 3;
  constexpr int PADW  = (SPANW + 3) & ~3;
  __shared__ float patch[8][SPAN][PADW];
  __shared__ float wlds[32][8][3][4];
  const int tid = threadIdx.x;
  const int tile = blockIdx.x;
  const int tx0 = (tile % TILES_X) * TW, ty0 = (tile / TILES_X) * TH;
  const int ocb = blockIdx.y * 32;
  const int cb0 = blockIdx.z * CSPL;
  const int ocg = tid >> 5, cell = tid & 31;
  const int cx = cell & 3, cy = cell >> 2;
  float acc[4][2][4] = {};
  for (int cc = 0; cc < CSPL / 8; ++cc) {
    int cbase = cb0 + cc * 8;
    __syncthreads();
    for (int idx = tid; idx < 8 * SPAN * PADW; idx += 256) {
      int ch = idx / (SPAN * PADW);
      int rem = idx - ch * (SPAN * PADW);
      int r = rem / PADW;
      int col = rem - r * PADW;
      float v = 0.f;
      int iy = ty0 * STR - 1 + r, ix = tx0 * STR - 1 + col;
      if (col < SPANW && iy >= 0 && iy < HIN && ix >= 0 && ix < HIN)
        v = in[(size_t)(cbase + ch) * (HIN * HIN) + iy * HIN + ix];
      (&patch[0][0][0])[idx] = v;
    }
    for (int idx = tid; idx < 32 * 8 * 3 * 4; idx += 256) {
      int oc = idx / 96;
      int rem = idx - oc * 96;
      int ch = rem / 12;
      int rem2 = rem - ch * 12;
      int ky = rem2 >> 2, kx = rem2 & 3;
      (&wlds[0][0][0][0])[idx] = (kx < 3)
        ? w[((size_t)(ocb + oc) * CIN + cbase + ch) * 9 + ky * 3 + kx] : 0.f;
    }
    __syncthreads();
    #pragma unroll 1
    for (int ch = 0; ch < 8; ++ch) {
      #pragma unroll
      for (int ky = 0; ky < 3; ++ky) {
        constexpr int NF = (STR == 2) ? 3 : 2;
        const float* p0 = &patch[ch][(cy * 2 + 0) * STR + ky][cx * 4 * STR];
        const float* p1 = &patch[ch][(cy * 2 + 1) * STR + ky][cx * 4 * STR];
        f4 a0[NF], a1[NF];
        #pragma unroll
        for (int q = 0; q < NF; ++q) { a0[q] = *(const f4*)(p0 + q * 4); a1[q] = *(const f4*)(p1 + q * 4); }
        #pragma unroll
        for (int oc = 0; oc < 4; ++oc) {
          f4 wv = *(const f4*)&wlds[ocg * 4 + oc][ch][ky][0];
          #pragma unroll
          for (int kx = 0; kx < 3; ++kx) {
            #pragma unroll
            for (int x = 0; x < 4; ++x) {
              int e = x * STR + kx;
              acc[oc][0][x] += a0[e >> 2][e & 3] * wv[kx];
              acc[oc][1][x] += a1[e >> 2][e & 3] * wv[kx];
            }
          }
        }
      }
    }
  }
  size_t zb = (size_t)blockIdx.z * COUT * HOUT * HOUT;
  #pragma unroll
  for (int oc = 0; oc < 4; ++oc) {
    #pragma unroll
    for (int r = 0; r < 2; ++r) {
      f4 v;
      #pragma unroll
      for (int x = 0; x < 4; ++x) v[x] = acc[oc][r][x];
      *(f4*)&parts[zb + (size_t)(ocb + ocg * 4 + oc) * (HOUT * HOUT)
                   + (size_t)(ty0 + cy * 2 + r) * HOUT + tx0 + cx * 4] = v;
    }
  }
}

// ---- partial-sum + bias + relu, f4-vectorized (+ optional NHWC emits) ------
template<int NS>
__global__ __launch_bounds__(256) void reduce_conv_kernel(
    const float* __restrict__ parts, const float* __restrict__ bias,
    float* __restrict__ out, int total4, int hwshift,
    unsigned short* __restrict__ nhwc, float* __restrict__ nhwc32, int C) {
  int i4 = blockIdx.x * 256 + threadIdx.x;
  if (i4 >= total4) return;
  const f4* p4 = (const f4*)parts;
  f4 s = {0.f, 0.f, 0.f, 0.f};
  #pragma unroll
  for (int k = 0; k < NS; ++k) s += p4[(size_t)k * total4 + i4];
  int i = i4 * 4;
  int c = i >> hwshift;
  float b = bias[c];
  #pragma unroll
  for (int j = 0; j < 4; ++j) s[j] = fmaxf(s[j] + b, 0.f);
  ((f4*)out)[i4] = s;
  int hw = 1 << hwshift;
  int px = i & (hw - 1);
  if (nhwc) {
    #pragma unroll
    for (int j = 0; j < 4; ++j) nhwc[(size_t)(px + j) * C + c] = f2bf(s[j]);
  }
  if (nhwc32) {
    #pragma unroll
    for (int j = 0; j < 4; ++j) nhwc32[(size_t)(px + j) * C + c] = s[j];
  }
}

// ------------------------------ RPN 1x1 heads (reads t in NHWC fp32) -------
__global__ __launch_bounds__(64) void rpn_head_kernel(
    const float* __restrict__ tn, const float* __restrict__ wc,
    const float* __restrict__ bc, const float* __restrict__ wb,
    const float* __restrict__ bb, float* __restrict__ objf,
    float* __restrict__ bdf) {
  int px = blockIdx.x, lane = threadIdx.x;
  float acc[45] = {};
  for (int j = 0; j < 8; ++j) {
    int c = j * 64 + lane;
    float tv = tn[px * 512 + c];
    #pragma unroll
    for (int a = 0; a < 9; ++a) acc[a] += tv * wc[a * 512 + c];
    #pragma unroll
    for (int o = 0; o < 36; ++o) acc[9 + o] += tv * wb[o * 512 + c];
  }
  #pragma unroll
  for (int o = 0; o < 45; ++o) {
    #pragma unroll
    for (int m = 32; m; m >>= 1) acc[o] += __shfl_xor(acc[o], m);
  }
  if (lane == 0) {
    #pragma unroll
    for (int a = 0; a < 9; ++a) objf[px * 9 + a] = acc[a] + bc[a];
    #pragma unroll
    for (int a = 0; a < 9; ++a)
      #pragma unroll
      for (int q = 0; q < 4; ++q)
        bdf[(px * 9 + a) * 4 + q] = acc[9 + a * 4 + q] + bb[a * 4 + q];
  }
}

// ------------------------------ anchor decode -> props (pre-clipped) -------
__device__ const float g_W2[9] = {91.f, 181.f, 362.f, 64.f, 128.f, 256.f, 45.f, 91.f, 181.f};
__device__ const float g_H2[9] = {45.f, 91.f, 181.f, 64.f, 128.f, 256.f, 91.f, 181.f, 362.f};

__global__ __launch_bounds__(256) void props_kernel(
    const float* __restrict__ bdf, float* __restrict__ props) {
  int i = blockIdx.x * 256 + threadIdx.x;
  if (i >= 2304) return;
  int pix = i / 9; int a = i - pix * 9;
  int y = pix >> 4, x = pix & 15;
  float wid = 2.f * g_W2[a], hei = 2.f * g_H2[a];
  float cx = (float)(x * 32), cy = (float)(y * 32);
  float dx = bdf[i * 4 + 0], dy = bdf[i * 4 + 1];
  float dw = fminf(bdf[i * 4 + 2], BBOX_CLAMP_F);
  float dh = fminf(bdf[i * 4 + 3], BBOX_CLAMP_F);
  float pcx = dx * wid + cx, pcy = dy * hei + cy;
  float pw = expf(dw) * wid, ph = expf(dh) * hei;
  props[i * 4 + 0] = fminf(fmaxf(pcx - 0.5f * pw, 0.f), 512.f);
  props[i * 4 + 1] = fminf(fmaxf(pcy - 0.5f * ph, 0.f), 512.f);
  props[i * 4 + 2] = fminf(fmaxf(pcx + 0.5f * pw, 0.f), 512.f);
  props[i * 4 + 3] = fminf(fmaxf(pcy + 0.5f * ph, 0.f), 512.f);
}

// ------------------------------ exact stable top-1000 by rank --------------
__global__ __launch_bounds__(256) void topk_kernel(
    const float* __restrict__ objf, const float* __restrict__ props,
    float* __restrict__ rois) {
  __shared__ float v[2304];
  int tid = threadIdx.x;
  for (int idx = tid; idx < 2304; idx += 256) v[idx] = objf[idx];
  __syncthreads();
  int i = blockIdx.x * 256 + tid;
  float vi = v[i];
  int rank = 0;
  for (int j = 0; j < 2304; ++j) {
    float vj = v[j];
    rank += (vj > vi) || (vj == vi && j < i);
  }
  if (rank < 1000) {
    f4 p = *(const f4*)(props + i * 4);
    *(f4*)(rois + rank * 4) = p;
  }
}

// ---------------- ROI-align -> A (bf16, k = p*512 + c), coalesced ----------
// 256 threads = 2 pooled cells x 128 uint2 (4 channels each).
__global__ __launch_bounds__(256) void roi_align_kernel(
    const float* __restrict__ rois, const unsigned short* __restrict__ featn,
    unsigned short* __restrict__ A) {
  __shared__ int   pidx[49][16];   // uint2-unit offsets: (y*16+x)*128
  __shared__ float pwg[49][16];
  int m = blockIdx.x, tid = threadIdx.x;
  if (tid < 49) {
    int qy = tid / 7, qx = tid - qy * 7;
    float x1 = rois[m * 4 + 0] * 0.03125f;
    float y1 = rois[m * 4 + 1] * 0.03125f;
    float x2 = rois[m * 4 + 2] * 0.03125f;
    float y2 = rois[m * 4 + 3] * 0.03125f;
    float rw = fmaxf(x2 - x1, 1.f), rh = fmaxf(y2 - y1, 1.f);
    float wsx[2][2]; int xsx[2][2];
    float wsy[2][2]; int ysy[2][2];
    #pragma unroll
    for (int s = 0; s < 2; ++s) {
      float gx = ((float)(2 * qx + s) + 0.5f) / 14.f;
      float px = fminf(fmaxf(x1 + gx * rw, 0.f), 15.f);
      int x0 = (int)floorf(px);
      int x1i = min(x0 + 1, 15);
      float lx = px - (float)x0;
      xsx[s][0] = x0; xsx[s][1] = x1i; wsx[s][0] = 1.f - lx; wsx[s][1] = lx;
      float gy = ((float)(2 * qy + s) + 0.5f) / 14.f;
      float py = fminf(fmaxf(y1 + gy * rh, 0.f), 15.f);
      int y0 = (int)floorf(py);
      int y1i = min(y0 + 1, 15);
      float ly = py - (float)y0;
      ysy[s][0] = y0; ysy[s][1] = y1i; wsy[s][0] = 1.f - ly; wsy[s][1] = ly;
    }
    int e = 0;
    #pragma unroll
    for (int sy = 0; sy < 2; ++sy)
      #pragma unroll
      for (int cyi = 0; cyi < 2; ++cyi)
        #pragma unroll
        for (int sx = 0; sx < 2; ++sx)
          #pragma unroll
          for (int cxi = 0; cxi < 2; ++cxi) {
            pwg[tid][e] = 0.25f * wsy[sy][cyi] * wsx[sx][cxi];
            pidx[tid][e] = (ysy[sy][cyi] * 16 + xsx[sx][cxi]) * 128;
            ++e;
          }
  }
  __syncthreads();
  const uint2* F4 = (const uint2*)featn;   // 4 channels per uint2
  uint2* A4 = (uint2*)A;
  int cpair = tid & 127;
  int psel  = tid >> 7;
  size_t base = (size_t)m * 6272 + cpair;  // uint2 units per roi = 25088/4
  for (int p0 = 0; p0 < 49; p0 += 2) {
    int p = p0 + psel;
    if (p < 49) {
      float a0 = 0.f, a1 = 0.f, a2 = 0.f, a3 = 0.f;
      #pragma unroll
      for (int e = 0; e < 16; ++e) {
        uint2 u = F4[pidx[p][e] + cpair];
        float wgt = pwg[p][e];
        a0 += wgt * bf2f((unsigned short)(u.x & 0xffffu));
        a1 += wgt * bf2f((unsigned short)(u.x >> 16));
        a2 += wgt * bf2f((unsigned short)(u.y & 0xffffu));
        a3 += wgt * bf2f((unsigned short)(u.y >> 16));
      }
      uint2 o;
      o.x = (unsigned int)f2bf(a0) | ((unsigned int)f2bf(a1) << 16);
      o.y = (unsigned int)f2bf(a2) | ((unsigned int)f2bf(a3) << 16);
      A4[base + (size_t)p * 128] = o;
    }
  }
}

// --------- fc1_w (25088,1024) fp32 -> Bt1 (1024,25088) bf16, k=p*512+c -----
__global__ __launch_bounds__(256) void transpose_fc1_kernel(
    const float* __restrict__ src, unsigned short* __restrict__ dst) {
  __shared__ float tile[64][65];
  int p = blockIdx.x;              // 0..48
  int c0 = blockIdx.y * 64;        // 0..511
  int n0 = blockIdx.z * 64;        // 0..1023
  int tid = threadIdx.x;
  int rr = tid >> 4, c4 = tid & 15;
  #pragma unroll
  for (int j = 0; j < 4; ++j) {
    int c = rr + j * 16;
    f4 v = *(const f4*)(src + (size_t)((c0 + c) * 49 + p) * 1024 + n0 + c4 * 4);
    tile[c][c4 * 4 + 0] = v[0]; tile[c][c4 * 4 + 1] = v[1];
    tile[c][c4 * 4 + 2] = v[2]; tile[c][c4 * 4 + 3] = v[3];
  }
  __syncthreads();
  int nl = tid >> 2;
  int kc = (tid & 3) * 16;
  unsigned int u[8];
  #pragma unroll
  for (int i = 0; i < 8; ++i) {
    unsigned int lo = f2bf(tile[kc + 2 * i][nl]);
    unsigned int hi = f2bf(tile[kc + 2 * i + 1][nl]);
    u[i] = lo | (hi << 16);
  }
  uint4* dp = (uint4*)(dst + (size_t)(n0 + nl) * 25088 + p * 512 + c0 + kc);
  dp[0] = make_uint4(u[0], u[1], u[2], u[3]);
  dp[1] = make_uint4(u[4], u[5], u[6], u[7]);
}

// ------------------------------ fp32 (K,N) -> bf16 (N,K) transpose ---------
__global__ __launch_bounds__(256) void transpose_bf16_kernel(
    const float* __restrict__ src, unsigned short* __restrict__ dst,
    int K, int N) {
  __shared__ float tile[64][65];
  int k0 = blockIdx.x * 64, n0 = blockIdx.y * 64;
  int tid = threadIdx.x;
  int rr = tid >> 4, c4 = tid & 15;
  #pragma unroll
  for (int j = 0; j < 4; ++j) {
    int r = rr + j * 16;
    f4 v = *(const f4*)(src + (size_t)(k0 + r) * N + n0 + c4 * 4);
    tile[r][c4 * 4 + 0] = v[0]; tile[r][c4 * 4 + 1] = v[1];
    tile[r][c4 * 4 + 2] = v[2]; tile[r][c4 * 4 + 3] = v[3];
  }
  __syncthreads();
  int nl = tid >> 2;
  int kc = (tid & 3) * 16;
  unsigned int u[8];
  #pragma unroll
  for (int i = 0; i < 8; ++i) {
    unsigned int lo = f2bf(tile[kc + 2 * i][nl]);
    unsigned int hi = f2bf(tile[kc + 2 * i + 1][nl]);
    u[i] = lo | (hi << 16);
  }
  uint4* dp = (uint4*)(dst + (size_t)(n0 + nl) * K + k0 + kc);
  dp[0] = make_uint4(u[0], u[1], u[2], u[3]);
  dp[1] = make_uint4(u[4], u[5], u[6], u[7]);
}

// ------------- bf16 GEMM  C = A(MxK) * B^T(NxK), split-K partials ----------
// BF16P: partial tiles stored as bf16 (slab pitch 1024*1024 bf16), else fp32.
template<bool BF16P>
__global__ __launch_bounds__(256, 4) void gemm_bt_kernel(
    const unsigned short* __restrict__ A, const unsigned short* __restrict__ B,
    void* __restrict__ parts, int K, int nsteps) {
  __shared__ unsigned short As[128 * 32];
  __shared__ unsigned short Bs[128 * 32];
  const int tid = threadIdx.x;
  const int lane = tid & 63, wave = tid >> 6;
  const int n0 = blockIdx.x * 128, m0 = blockIdx.y * 128, ks = blockIdx.z;
  const int kbase = ks * nsteps * 32;
  f4 acc[4][4] = {};
  const int wr = wave >> 1, wc = wave & 1;
  const int rsel = lane & 15, ksel = (lane >> 4) * 8;
  for (int s = 0; s < nsteps; ++s) {
    int kk = kbase + s * 32;
    #pragma unroll
    for (int j = 0; j < 2; ++j) {
      int c_ = j * 256 + tid;
      int row = c_ >> 2;
      int k8 = (c_ & 3) << 3;
      __builtin_amdgcn_global_load_lds(
          (const __attribute__((address_space(1))) void*)(A + (size_t)(m0 + row) * K + kk + k8),
          (__attribute__((address_space(3))) void*)(As + c_ * 8), 16, 0, 0);
      __builtin_amdgcn_global_load_lds(
          (const __attribute__((address_space(1))) void*)(B + (size_t)(n0 + row) * K + kk + k8),
          (__attribute__((address_space(3))) void*)(Bs + c_ * 8), 16, 0, 0);
    }
    __syncthreads();
    s8v af[4], bfr[4];
    #pragma unroll
    for (int m = 0; m < 4; ++m)
      af[m] = *(const s8v*)(As + (wr * 64 + m * 16 + rsel) * 32 + ksel);
    #pragma unroll
    for (int n = 0; n < 4; ++n)
      bfr[n] = *(const s8v*)(Bs + (wc * 64 + n * 16 + rsel) * 32 + ksel);
    #pragma unroll
    for (int m = 0; m < 4; ++m)
      #pragma unroll
      for (int n = 0; n < 4; ++n)
        acc[m][n] = __builtin_amdgcn_mfma_f32_16x16x32_bf16(af[m], bfr[n], acc[m][n], 0, 0, 0);
    __syncthreads();
  }
  int rb = m0 + wr * 64 + ((lane >> 4) << 2);
  int cb = n0 + wc * 64 + (lane & 15);
  if constexpr (BF16P) {
    unsigned short* outp = (unsigned short*)parts + (size_t)ks * 1048576;
    #pragma unroll
    for (int m = 0; m < 4; ++m)
      #pragma unroll
      for (int n = 0; n < 4; ++n)
        #pragma unroll
        for (int i = 0; i < 4; ++i)
          outp[(size_t)(rb + m * 16 + i) * 1024 + cb + n * 16] = f2bf(acc[m][n][i]);
  } else {
    float* outp = (float*)parts + (size_t)ks * 1048576;
    #pragma unroll
    for (int m = 0; m < 4; ++m)
      #pragma unroll
      for (int n = 0; n < 4; ++n)
        #pragma unroll
        for (int i = 0; i < 4; ++i)
          outp[(size_t)(rb + m * 16 + i) * 1024 + cb + n * 16] = acc[m][n][i];
  }
}

// ------------------------------ GEMM reductions ----------------------------
__global__ __launch_bounds__(256) void reduce_fc1_kernel(
    const unsigned short* __restrict__ parts, const float* __restrict__ bias,
    unsigned short* __restrict__ h1b) {
  int i2 = blockIdx.x * 256 + threadIdx.x;        // uint2 index (4 bf16)
  const uint2* p2 = (const uint2*)parts;
  float s0 = 0.f, s1 = 0.f, s2 = 0.f, s3 = 0.f;
  #pragma unroll
  for (int k = 0; k < 16; ++k) {
    uint2 u = p2[(size_t)k * 262144 + i2];
    s0 += bf2f((unsigned short)(u.x & 0xffffu));
    s1 += bf2f((unsigned short)(u.x >> 16));
    s2 += bf2f((unsigned short)(u.y & 0xffffu));
    s3 += bf2f((unsigned short)(u.y >> 16));
  }
  f4 b = ((const f4*)bias)[i2 & 255];
  s0 += b[0]; s1 += b[1]; s2 += b[2]; s3 += b[3];
  unsigned int lo = (unsigned int)f2bf(fmaxf(s0, 0.f)) | ((unsigned int)f2bf(fmaxf(s1, 0.f)) << 16);
  unsigned int hi = (unsigned int)f2bf(fmaxf(s2, 0.f)) | ((unsigned int)f2bf(fmaxf(s3, 0.f)) << 16);
  ((uint2*)h1b)[i2] = make_uint2(lo, hi);
}

__global__ __launch_bounds__(256) void reduce_fc2_kernel(
    const float* __restrict__ parts, const float* __restrict__ bias,
    float* __restrict__ h2) {
  int i4 = blockIdx.x * 256 + threadIdx.x;
  const f4* p4 = (const f4*)parts;
  f4 s = p4[i4] + p4[262144 + i4];
  f4 b = ((const f4*)bias)[i4 & 255];
  s += b;
  #pragma unroll
  for (int j = 0; j < 4; ++j) s[j] = fmaxf(s[j], 0.f);
  ((f4*)h2)[i4] = s;
}

// ------------------------------ final heads + softmax + decode -------------
__global__ __launch_bounds__(256) void heads_kernel(
    const float* __restrict__ h2, const float* __restrict__ cw,
    const float* __restrict__ cb, const float* __restrict__ bw,
    const float* __restrict__ bb, const float* __restrict__ rois,
    float* __restrict__ outp) {
  int m = blockIdx.x, tid = threadIdx.x;
  int lane = tid & 63, wv = tid >> 6;
  __shared__ float vals[32];
  const float* hrow = h2 + (size_t)m * 1024;
  float acc[8] = {};
  for (int k = lane; k < 1024; k += 64) {
    float hv = hrow[k];
    #pragma unroll
    for (int j = 0; j < 8; ++j) {
      int o = wv * 8 + j;
      float wval = 0.f;
      if (o < 6) wval = cw[k * 6 + o];
      else if (o < 30) wval = bw[k * 24 + o - 6];
      acc[j] += hv * wval;
    }
  }
  #pragma unroll
  for (int j = 0; j < 8; ++j) {
    #pragma unroll
    for (int s = 32; s; s >>= 1) acc[j] += __shfl_xor(acc[j], s);
  }
  if (lane == 0) {
    #pragma unroll
    for (int j = 0; j < 8; ++j) {
      int o = wv * 8 + j;
      if (o < 6) vals[o] = acc[j] + cb[o];
      else if (o < 30) vals[o] = acc[j] + bb[o - 6];
    }
  }
  __syncthreads();
  if (tid < 5) {
    int cls = tid + 1;
    float mx = vals[0];
    #pragma unroll
    for (int o = 1; o < 6; ++o) mx = fmaxf(mx, vals[o]);
    float den = 0.f;
    #pragma unroll
    for (int o = 0; o < 6; ++o) den += expf(vals[o] - mx);
    float score = expf(vals[cls] - mx) / den;
    float x1 = rois[m * 4 + 0], y1 = rois[m * 4 + 1];
    float x2 = rois[m * 4 + 2], y2 = rois[m * 4 + 3];
    float w_ = x2 - x1, h_ = y2 - y1;
    float cxx = x1 + 0.5f * w_, cyy = y1 + 0.5f * h_;
    float dx = vals[6 + cls * 4 + 0] / 10.f;
    float dy = vals[6 + cls * 4 + 1] / 10.f;
    float dw = fminf(vals[6 + cls * 4 + 2] / 5.f, BBOX_CLAMP_F);
    float dh = fminf(vals[6 + cls * 4 + 3] / 5.f, BBOX_CLAMP_F);
    float pcx = dx * w_ + cxx, pcy = dy * h_ + cyy;
    float pw = expf(dw) * w_, ph = expf(dh) * h_;
    float* op = outp + m * 25 + tid * 5;
    op[0] = fminf(fmaxf(pcx - 0.5f * pw, 0.f), 512.f);
    op[1] = fminf(fmaxf(pcy - 0.5f * ph, 0.f), 512.f);
    op[2] = fminf(fmaxf(pcx + 0.5f * pw, 0.f), 512.f);
    op[3] = fminf(fmaxf(pcy + 0.5f * ph, 0.f), 512.f);
    op[4] = score;
  }
}

// ---------------------------------------------------------------------------
// workspace layout (bytes). Total ~140 MB with heavy overlap.
// ---------------------------------------------------------------------------
static constexpr size_t MB_ = 1024ull * 1024ull;
static constexpr size_t A_OFF      = 0;
static constexpr size_t CONV0_OFF  = 0;
static constexpr size_t POOL_OFF   = 17 * MB_;
static constexpr size_t C1_OFF     = 22 * MB_;
static constexpr size_t C2_OFF     = 25 * MB_;
static constexpr size_t CPARTS_OFF = 27 * MB_;   // up to 16 MB of partials
static constexpr size_t FEAT_OFF   = 52 * MB_;
static constexpr size_t FEATN_OFF  = FEAT_OFF + 524288;
static constexpr size_t T_OFF      = FEATN_OFF + 262144;
static constexpr size_t OBJF_OFF   = T_OFF + 524288;
static constexpr size_t BDF_OFF    = OBJF_OFF + 16384;
static constexpr size_t PROPS_OFF  = BDF_OFF + 40960;
static constexpr size_t ROIS_OFF   = PROPS_OFF + 40960;
static constexpr size_t TN_OFF     = ROIS_OFF + 16384;     // t NHWC fp32, 512KB
static constexpr size_t BT1_OFF    = 54 * MB_;
static constexpr size_t H1B_OFF    = BT1_OFF;              // after GEMM1
static constexpr size_t BT2_OFF    = BT1_OFF + 2 * MB_;
static constexpr size_t PARTS2_OFF = BT1_OFF + 4 * MB_;
static constexpr size_t H2_OFF     = BT1_OFF + 13 * MB_;
static constexpr size_t PARTS1_OFF = 106 * MB_;            // 16 x 2MB bf16

extern "C" void kernel_launch(void* const* d_in, const int* in_sizes, int n_in,
                              void* d_out, int out_size, void* d_ws, size_t ws_size,
                              hipStream_t stream) {
  (void)in_sizes; (void)n_in; (void)out_size; (void)ws_size;
  const float* images     = (const float*)d_in[0];
  const float* c0_w       = (const float*)d_in[1];
  const float* c0_b       = (const float*)d_in[2];
  const float* c1_w       = (const float*)d_in[3];
  const float* c1_b       = (const float*)d_in[4];
  const float* c2_w       = (const float*)d_in[5];
  const float* c2_b       = (const float*)d_in[6];
  const float* c3_w       = (const float*)d_in[7];
  const float* c3_b       = (const float*)d_in[8];
  const float* rpn_conv_w = (const float*)d_in[9];
  const float* rpn_conv_b = (const float*)d_in[10];
  const float* rpn_cls_w  = (const float*)d_in[11];
  const float* rpn_cls_b  = (const float*)d_in[12];
  const float* rpn_bbox_w = (const float*)d_in[13];
  const float* rpn_bbox_b = (const float*)d_in[14];
  const float* fc1_w      = (const float*)d_in[15];
  const float* fc1_b      = (const float*)d_in[16];
  const float* fc2_w      = (const float*)d_in[17];
  const float* fc2_b      = (const float*)d_in[18];
  const float* cls_w      = (const float*)d_in[19];
  const float* cls_b      = (const float*)d_in[20];
  const float* bbox_w     = (const float*)d_in[21];
  const float* bbox_b     = (const float*)d_in[22];

  char* ws = (char*)d_ws;
  float* conv0  = (float*)(ws + CONV0_OFF);
  float* pool   = (float*)(ws + POOL_OFF);
  float* c1o    = (float*)(ws + C1_OFF);
  float* c2o    = (float*)(ws + C2_OFF);
  float* cparts = (float*)(ws + CPARTS_OFF);
  float* feat   = (float*)(ws + FEAT_OFF);
  unsigned short* featn = (unsigned short*)(ws + FEATN_OFF);
  float* tbuf   = (float*)(ws + T_OFF);
  float* objf   = (float*)(ws + OBJF_OFF);
  float* bdf    = (float*)(ws + BDF_OFF);
  float* props  = (float*)(ws + PROPS_OFF);
  float* rois   = (float*)(ws + ROIS_OFF);
  float* tn     = (float*)(ws + TN_OFF);
  unsigned short* Abuf = (unsigned short*)(ws + A_OFF);
  unsigned short* Bt1  = (unsigned short*)(ws + BT1_OFF);
  unsigned short* h1b  = (unsigned short*)(ws + H1B_OFF);
  unsigned short* Bt2  = (unsigned short*)(ws + BT2_OFF);
  unsigned short* parts1b = (unsigned short*)(ws + PARTS1_OFF);
  float* parts2 = (float*)(ws + PARTS2_OFF);
  float* h2     = (float*)(ws + H2_OFF);
  float* outp   = (float*)d_out;

  // backbone (convs split CIN over grid.z for occupancy)
  conv0_kernel<<<dim3(16, 16, 2), 256, 0, stream>>>(images, c0_w, c0_b, conv0);
  maxpool_kernel<<<4096, 256, 0, stream>>>(conv0, pool);
  conv3x3_kernel<64, 128, 128, 64, 2, 4, 8><<<dim3(16, 4, 8), 256, 0, stream>>>(pool, c1_w, cparts);
  reduce_conv_kernel<8><<<512, 256, 0, stream>>>(cparts, c1_b, c1o, 131072, 12, nullptr, nullptr, 0);
  conv3x3_kernel<128, 256, 64, 32, 2, 2, 8><<<dim3(4, 8, 16), 256, 0, stream>>>(c1o, c2_w, cparts);
  reduce_conv_kernel<16><<<256, 256, 0, stream>>>(cparts, c2_b, c2o, 65536, 10, nullptr, nullptr, 0);
  conv3x3_kernel<256, 512, 32, 16, 2, 1, 8><<<dim3(1, 16, 32), 256, 0, stream>>>(c2o, c3_w, cparts);
  reduce_conv_kernel<32><<<128, 256, 0, stream>>>(cparts, c3_b, feat, 32768, 8, featn, nullptr, 512);

  // RPN
  conv3x3_kernel<512, 512, 16, 16, 1, 1, 16><<<dim3(1, 16, 32), 256, 0, stream>>>(feat, rpn_conv_w, cparts);
  reduce_conv_kernel<32><<<128, 256, 0, stream>>>(cparts, rpn_conv_b, tbuf, 32768, 8, nullptr, tn, 512);
  rpn_head_kernel<<<256, 64, 0, stream>>>(tn, rpn_cls_w, rpn_cls_b, rpn_bbox_w, rpn_bbox_b, objf, bdf);
  props_kernel<<<9, 256, 0, stream>>>(bdf, props);
  topk_kernel<<<9, 256, 0, stream>>>(objf, props, rois);

  // ROI features (A), pad rows 1000..1023 to zero
  hipMemsetAsync(ws + A_OFF + (size_t)1000 * 25088 * 2, 0, (size_t)24 * 25088 * 2, stream);
  roi_align_kernel<<<1000, 256, 0, stream>>>(rois, featn, Abuf);

  // fc1: (1024x25088) x (25088x1024), K permuted as p*512+c on both sides
  transpose_fc1_kernel<<<dim3(49, 8, 16), 256, 0, stream>>>(fc1_w, Bt1);
  gemm_bt_kernel<true><<<dim3(8, 8, 16), 256, 0, stream>>>(Abuf, Bt1, parts1b, 25088, 49);
  reduce_fc1_kernel<<<1024, 256, 0, stream>>>(parts1b, fc1_b, h1b);

  // fc2: (1024x1024) x (1024x1024)
  transpose_bf16_kernel<<<dim3(16, 16), 256, 0, stream>>>(fc2_w, Bt2, 1024, 1024);
  gemm_bt_kernel<false><<<dim3(8, 8, 2), 256, 0, stream>>>(h1b, Bt2, parts2, 1024, 16);
  reduce_fc2_kernel<<<1024, 256, 0, stream>>>(parts2, fc2_b, h2);

  // heads + final boxes/scores
  heads_kernel<<<1000, 256, 0, stream>>>(h2, cls_w, cls_b, bbox_w, bbox_b, rois, outp);
}